// Round 3
// baseline (388.362 us; speedup 1.0000x reference)
//
#include <hip/hip_runtime.h>

// ---------------------------------------------------------------------------
// CorefPairScorer: B=4, T=4096, D=768, N=256, HID=200 (padded to 224)
// h1(i,j) = relu(A[i] + Bv[j] + (emb_i*emb_j)@W1bot + b1)
// h2 = relu(h1@W2 + b2); s = h2@W3 + b3; masked softmax rows.
// R8: DMA weights -> neutral. R9: acc[4][7] -> scratch spill (WRITE 41MB),
//     neutral. Invariant across R7/R8/R9: ~2 blocks/CU resident, latency-
//     bound (MfmaUtil 11% matches 2-wave/SIMD model exactly).
// R10: residency x2. Drop smW/DMA (weights = coalesced global L2 reads),
//     LDS 57.8->31 KB; acc[2][7] 4-pass; Ai/Bv reloaded per pass into regs
//     (not persistent); __launch_bounds__(256,4) -> VGPR<=128, 4 blocks/CU.
//     Barriers: 2 per pass (8 total).
// ---------------------------------------------------------------------------

#define NB 4
#define NN 256
#define DD 768
#define TT 4096
#define HP 224
#define NTILES 14
#define KT1 24
#define KT2 7
#define TRI 136
#define ABS 448          // AB row stride (bf16): [A(224) | B(224)]
#define MTS 3584         // shorts per packed Mtile (16 rows x 224)

typedef __attribute__((ext_vector_type(8))) short short8;
typedef __attribute__((ext_vector_type(4))) float f32x4;

union FragU { uint4 u; short8 s; };

__device__ __forceinline__ float bf2f(unsigned short x) {
    return __uint_as_float(((unsigned int)x) << 16);
}
__device__ __forceinline__ unsigned short f2bf(float f) {
    unsigned int u = __float_as_uint(f);
    u += 0x7fffu + ((u >> 16) & 1u);   // RNE
    return (unsigned short)(u >> 16);
}
__device__ __forceinline__ float blo(unsigned int v) { return __uint_as_float(v << 16); }
__device__ __forceinline__ float bhi(unsigned int v) { return __uint_as_float(v & 0xffff0000u); }
// packed bf16 pair: (a*b) with pre-unpacked b halves; truncating pack via v_perm
__device__ __forceinline__ unsigned int mulpack(unsigned int a, float bl, float bh) {
    unsigned int m0 = __float_as_uint(blo(a) * bl);
    unsigned int m1 = __float_as_uint(bhi(a) * bh);
    return __builtin_amdgcn_perm(m1, m0, 0x07060302u);
}

// ---------------------------------------------------------------------------
// K0 (merged): weight swizzle (blocks 0..2211) + gather/cast (blocks 2212..3235)
//   frag layout: buf[((kt*NT+nt)*64+lane)*8+j] = W[kt*32+(lane>>4)*8+j][nt*16+(lane&15)]
// ---------------------------------------------------------------------------
__global__ void prep_all(const float* __restrict__ W1, const float* __restrict__ W2,
                         const float* __restrict__ ee, const int* __restrict__ eidx,
                         unsigned short* __restrict__ w1n,
                         unsigned short* __restrict__ w1s,
                         unsigned short* __restrict__ w2s,
                         unsigned short* __restrict__ emb) {
    const int N1n = 24 * 28 * 512;   // 344064
    const int N1s = 24 * 14 * 512;   // 172032
    const int N2  = 7 * 14 * 512;    // 50176
    int bx = blockIdx.x;
    if (bx >= 2212) {                 // gather + fp32->bf16
        int g = bx - 2212;
        int b = g >> 8, n = g & 255;
        int t = eidx[b * NN + n];
        const float* src = ee + ((size_t)b * TT + t) * DD;
        unsigned short* dst = emb + ((size_t)b * NN + n) * DD;
        for (int e = threadIdx.x; e < DD; e += 256) dst[e] = f2bf(src[e]);
        return;
    }
    int idx = bx * 256 + threadIdx.x;
    if (idx < N1n) {
        int j = idx & 7, lane = (idx >> 3) & 63, f = idx >> 9;
        int nt = f % 28, kt = f / 28;
        int k = kt * 32 + (lane >> 4) * 8 + j;     // 0..767
        int n = nt * 16 + (lane & 15);             // 0..447
        float v;
        if (n < HP) v = (n < 200) ? W1[(size_t)k * 200 + n] : 0.f;
        else { int c2 = n - HP; v = (c2 < 200) ? W1[(size_t)(768 + k) * 200 + c2] : 0.f; }
        w1n[idx] = f2bf(v);
    } else if (idx < N1n + N1s) {
        int i2 = idx - N1n;
        int j = i2 & 7, lane = (i2 >> 3) & 63, f = i2 >> 9;
        int nt = f % NTILES, kt = f / NTILES;
        int k = kt * 32 + (lane >> 4) * 8 + j;
        int n = nt * 16 + (lane & 15);
        float v = (n < 200) ? W1[(size_t)(1536 + k) * 200 + n] : 0.f;
        w1s[i2] = f2bf(v);
    } else if (idx < N1n + N1s + N2) {
        int i2 = idx - N1n - N1s;
        int j = i2 & 7, lane = (i2 >> 3) & 63, f = i2 >> 9;
        int nt = f % NTILES, kt = f / NTILES;
        int k = kt * 32 + (lane >> 4) * 8 + j;
        int n = nt * 16 + (lane & 15);
        float v = (k < 200 && n < 200) ? W2[(size_t)k * 200 + n] : 0.f;
        w2s[i2] = f2bf(v);
    }
}

// ---------------------------------------------------------------------------
// K2: AB = emb(1024x768) @ [W1top|W1mid](768x448), bf16 MFMA, bf16 out.
//   256 one-wave blocks (mtile 0..63 x ngroup 0..3) -> all CUs busy.
// ---------------------------------------------------------------------------
__global__ __launch_bounds__(64)
void node_mfma(const unsigned short* __restrict__ emb,
               const unsigned short* __restrict__ w1n,
               unsigned short* __restrict__ AB) {
    int lane = threadIdx.x & 63;
    int q = lane >> 4, c = lane & 15;
    int mt = blockIdx.x >> 2;         // 0..63
    int ng = blockIdx.x & 3;          // 0..3
    int m0 = mt * 16;
    const uint4* ga = (const uint4*)emb + (size_t)(m0 + c) * 96;
    const uint4* gb = (const uint4*)w1n;

    f32x4 acc[7];
#pragma unroll
    for (int n = 0; n < 7; ++n) acc[n] = (f32x4){0.f, 0.f, 0.f, 0.f};

    for (int kt = 0; kt < KT1; ++kt) {
        FragU a; a.u = ga[kt * 4 + q];
#pragma unroll
        for (int n = 0; n < 7; ++n) {
            FragU bb; bb.u = gb[((kt * 28 + ng * 7 + n) << 6) + lane];
            acc[n] = __builtin_amdgcn_mfma_f32_16x16x32_bf16(a.s, bb.s, acc[n], 0, 0, 0);
        }
    }
#pragma unroll
    for (int n = 0; n < 7; ++n) {
        int col = (ng * 7 + n) * 16 + c;
#pragma unroll
        for (int rr = 0; rr < 4; ++rr)
            AB[(size_t)(m0 + q * 4 + rr) * ABS + col] = f2bf(acc[n][rr]);
    }
}

// ---------------------------------------------------------------------------
// K3: fused pair MLP per 16x16 (i,j) tile. 256 threads = 4 waves.
//   4 passes of 4 Mtiles. Wave (mp = w>>1, nh = w&1) owns Mtiles
//   {pass*4+2mp, pass*4+2mp+1}, ntile-half nh; acc[2][7].
//   Weights read straight from global (L2-resident, coalesced 1KB/wave).
//   LDS: smH (h1 frag-packed, 4 slots) + sred only = 31 KB -> 4 blocks/CU
//   with VGPR<=128 (__launch_bounds__(256,4)). 2 barriers per pass.
// ---------------------------------------------------------------------------
__global__ __launch_bounds__(256, 4)
void pair_mlp(
    const unsigned short* __restrict__ emb,
    const unsigned short* __restrict__ w1s,
    const unsigned short* __restrict__ w2s,
    const unsigned short* __restrict__ AB,
    const float* __restrict__ b1, const float* __restrict__ b2,
    const float* __restrict__ W3, const float* __restrict__ b3,
    float* __restrict__ S) {
    int z = blockIdx.x;
    int b = z / TRI;
    int r = z % TRI;
    int ti = (int)((sqrtf(8.f * (float)r + 1.f) - 1.f) * 0.5f);
    while ((ti + 1) * (ti + 2) / 2 <= r) ++ti;
    while (ti * (ti + 1) / 2 > r) --ti;
    int tj = r - ti * (ti + 1) / 2;
    int i0 = ti << 4, j0 = tj << 4;

    int tid = threadIdx.x;
    int lane = tid & 63;
    int w = tid >> 6;                 // 0..3
    int q = lane >> 4, c = lane & 15;
    int mp = w >> 1, nh = w & 1;

    __shared__ __align__(16) unsigned short smH[4 * MTS];    // 28672 B h1 (4 Mtile slots)
    __shared__ float sred[2][64];                            //   512 B

    const uint4* w1f = (const uint4*)w1s;
    const uint4* w2f = (const uint4*)w2s;
    const uint4* gI  = (const uint4*)(emb + ((size_t)b * NN + i0) * DD);
    const uint4* gJc = (const uint4*)(emb + ((size_t)b * NN + j0 + c) * DD); // per-lane row

    for (int pass = 0; pass < 4; ++pass) {
        // ---- phase 1: acc[2][7] over K=768, weights from global ----
        f32x4 acc[2][7];
#pragma unroll
        for (int t = 0; t < 2; ++t)
#pragma unroll
            for (int n = 0; n < 7; ++n)
                acc[t][n] = (f32x4){0.f, 0.f, 0.f, 0.f};

        for (int kt = 0; kt < KT1; ++kt) {
            uint4 bfr[7];
#pragma unroll
            for (int n = 0; n < 7; ++n)
                bfr[n] = w1f[(kt * NTILES + nh * 7 + n) * 64 + lane];
            uint4 ej = gJc[kt * 4 + q];
            float exl = blo(ej.x), exh = bhi(ej.x);
            float eyl = blo(ej.y), eyh = bhi(ej.y);
            float ezl = blo(ej.z), ezh = bhi(ej.z);
            float ewl = blo(ej.w), ewh = bhi(ej.w);
#pragma unroll
            for (int t = 0; t < 2; ++t) {
                uint4 ei = gI[(pass * 4 + mp * 2 + t) * 96 + kt * 4 + q]; // quad-broadcast
                FragU a;
                a.u.x = mulpack(ei.x, exl, exh);
                a.u.y = mulpack(ei.y, eyl, eyh);
                a.u.z = mulpack(ei.z, ezl, ezh);
                a.u.w = mulpack(ei.w, ewl, ewh);
#pragma unroll
                for (int n = 0; n < 7; ++n) {
                    FragU bb; bb.u = bfr[n];
                    acc[t][n] = __builtin_amdgcn_mfma_f32_16x16x32_bf16(a.s, bb.s, acc[t][n], 0, 0, 0);
                }
            }
        }

        // ---- Ai / Bv(+b1) packed bf16 regs (reloaded per pass; L1/L2-hit) ----
        unsigned int aiP[7];
        {
            size_t rowL = (size_t)(b * NN + i0 + pass * 4 + mp * 2);
#pragma unroll
            for (int n = 0; n < 7; ++n) {
                int h = ((nh * 7 + n) << 4) + c;
                aiP[n] = ((unsigned int)AB[(rowL + 1) * ABS + h] << 16) |
                         (unsigned int)AB[rowL * ABS + h];
            }
        }
        unsigned int bvP[2][7];
#pragma unroll
        for (int rp = 0; rp < 2; ++rp)
#pragma unroll
            for (int n = 0; n < 7; ++n) {
                int h = ((nh * 7 + n) << 4) + c;
                float bb1 = (h < 200) ? b1[h] : 0.f;
                float lo = bf2f(AB[(size_t)(b * NN + j0 + q * 4 + 2 * rp) * ABS + HP + h]) + bb1;
                float hi = bf2f(AB[(size_t)(b * NN + j0 + q * 4 + 2 * rp + 1) * ABS + HP + h]) + bb1;
                bvP[rp][n] = ((unsigned int)f2bf(hi) << 16) | (unsigned int)f2bf(lo);
            }

        // ---- epilogue: h1 = relu(acc + Ai + Bv) -> smH (frag-packed bf16) ----
        // (write-after-read hazard vs previous pass's ph2 covered by B2 of
        //  the previous pass)
#pragma unroll
        for (int t = 0; t < 2; ++t) {
            int lt = mp * 2 + t;
#pragma unroll
            for (int n = 0; n < 7; ++n) {
                int h = ((nh * 7 + n) << 4) + c;
                float aif = t ? bhi(aiP[n]) : blo(aiP[n]);
                int kk2 = h >> 5, q2 = (h >> 3) & 3, j2 = h & 7;
                int fa = lt * MTS + ((kk2 * 4 + q2) << 7) + j2;
#pragma unroll
                for (int rr = 0; rr < 4; ++rr) {
                    float bvf = (rr & 1) ? bhi(bvP[rr >> 1][n]) : blo(bvP[rr >> 1][n]);
                    float v = acc[t][n][rr] + aif + bvf;
                    v = fmaxf(v, 0.f);
                    smH[fa + ((q * 4 + rr) << 3)] = f2bf(v);
                }
            }
        }
        __syncthreads();   // B1: smH written -> ph2 may read

        // ---- phase 2: acc2[2][7] over K=224, weights from global ----
        f32x4 acc2[2][7];
#pragma unroll
        for (int u = 0; u < 2; ++u)
#pragma unroll
            for (int n = 0; n < 7; ++n)
                acc2[u][n] = (f32x4){0.f, 0.f, 0.f, 0.f};

        for (int kk = 0; kk < KT2; ++kk) {
            uint4 bfr2[7];
#pragma unroll
            for (int n = 0; n < 7; ++n)
                bfr2[n] = w2f[(kk * NTILES + nh * 7 + n) * 64 + lane];
#pragma unroll
            for (int u = 0; u < 2; ++u) {
                int lt = mp * 2 + u;
                FragU a2;
                a2.u = *(const uint4*)(&smH[lt * MTS + (((kk * 4 + q) * 16 + c) << 3)]);
#pragma unroll
                for (int n = 0; n < 7; ++n) {
                    FragU bb; bb.u = bfr2[n];
                    acc2[u][n] = __builtin_amdgcn_mfma_f32_16x16x32_bf16(a2.s, bb.s, acc2[u][n], 0, 0, 0);
                }
            }
        }

        // ---- phase 3: s = relu(h2 + b2) . W3, reduce cols via shfl ----
#pragma unroll
        for (int u = 0; u < 2; ++u) {
#pragma unroll
            for (int rr = 0; rr < 4; ++rr) {
                float part = 0.f;
#pragma unroll
                for (int n = 0; n < 7; ++n) {
                    int h = ((nh * 7 + n) << 4) + c;
                    float b2v = (h < 200) ? b2[h] : 0.f;
                    float w3v = (h < 200) ? W3[h] : 0.f;
                    float hv = fmaxf(acc2[u][n][rr] + b2v, 0.f);
                    part += hv * w3v;
                }
                part += __shfl_xor(part, 1);
                part += __shfl_xor(part, 2);
                part += __shfl_xor(part, 4);
                part += __shfl_xor(part, 8);
                if (c == 0)
                    sred[nh][((mp * 2 + u) << 4) + q * 4 + rr] = part;
            }
        }
        __syncthreads();   // B2: sred written -> store; also fences smH reuse

        // ---- store this pass's 64 pairs ----
        if (tid < 64) {
            int lt = tid >> 4;
            int i = i0 + pass * 4 + lt;
            int j = j0 + (tid & 15);
            S[((size_t)b * NN + i) * NN + j] = sred[0][tid] + sred[1][tid] + b3[0];
        }
        // store-read vs next pass's ph3-write separated by next pass's B1
    }
}

// ---------------------------------------------------------------------------
// K4: masked softmax per row; diag logit = 0; invalid -> -1000
// ---------------------------------------------------------------------------
__global__ __launch_bounds__(256) void softmax_rows(const float* __restrict__ S,
                                                    float* __restrict__ out) {
    int b = blockIdx.x >> 8, i = blockIdx.x & 255;
    int j = threadIdx.x;
    int lane = j & 63, w = j >> 6;
    __shared__ float red[16];
    float x = (j < i) ? S[((size_t)b * NN + i) * NN + j] : ((j == i) ? 0.f : -1e30f);
    float m = x;
#pragma unroll
    for (int off = 32; off; off >>= 1) m = fmaxf(m, __shfl_xor(m, off));
    if (lane == 0) red[w] = m;
    __syncthreads();
    float mx = fmaxf(fmaxf(red[0], red[1]), fmaxf(red[2], red[3]));
    float e = (j <= i) ? __expf(x - mx) : 0.f;
    float s = e;
#pragma unroll
    for (int off = 32; off; off >>= 1) s += __shfl_xor(s, off);
    if (lane == 0) red[8 + w] = s;
    __syncthreads();
    float sum = red[8] + red[9] + red[10] + red[11];
    out[((size_t)b * NN + i) * NN + j] = (j <= i) ? (e / sum) : -1000.0f;
}

// ---------------------------------------------------------------------------
extern "C" void kernel_launch(void* const* d_in, const int* in_sizes, int n_in,
                              void* d_out, int out_size, void* d_ws, size_t ws_size,
                              hipStream_t stream) {
    const float* ee  = (const float*)d_in[0];
    const int*   eidx = (const int*)d_in[1];
    const float* W1  = (const float*)d_in[2];
    const float* b1  = (const float*)d_in[3];
    const float* W2  = (const float*)d_in[4];
    const float* b2  = (const float*)d_in[5];
    const float* W3  = (const float*)d_in[6];
    const float* b3  = (const float*)d_in[7];
    float* out = (float*)d_out;

    char* p = (char*)d_ws;
    unsigned short* emb = (unsigned short*)p; p += (size_t)NB * NN * DD * 2;       // 1.5 MB
    unsigned short* w1n = (unsigned short*)p; p += (size_t)24 * 28 * 512 * 2;      // 672 KB
    unsigned short* w1s = (unsigned short*)p; p += (size_t)24 * 14 * 512 * 2;      // 336 KB
    unsigned short* w2s = (unsigned short*)p; p += (size_t)7 * 14 * 512 * 2;       // 98 KB
    unsigned short* AB  = (unsigned short*)p; p += (size_t)NB * NN * ABS * 2;      // 896 KB
    float* S  = (float*)p; p += (size_t)NB * NN * NN * 4;                           // 1 MB

    prep_all<<<3236, 256, 0, stream>>>(W1, W2, ee, eidx, w1n, w1s, w2s, emb);
    node_mfma<<<256, 64, 0, stream>>>(emb, w1n, AB);
    pair_mlp<<<NB * TRI, 256, 0, stream>>>(emb, w1s, w2s, AB, b1, b2, W3, b3, S);
    softmax_rows<<<NB * NN, 256, 0, stream>>>(S, out);
}

// Round 5
// 335.477 us; speedup vs baseline: 1.1576x; 1.1576x over previous
//
#include <hip/hip_runtime.h>

// ---------------------------------------------------------------------------
// CorefPairScorer: B=4, T=4096, D=768, N=256, HID=200 (padded to 224)
// h1(i,j) = relu(A[i] + Bv[j] + (emb_i*emb_j)@W1bot + b1)
// h2 = relu(h1@W2 + b2); s = h2@W3 + b3; masked softmax rows.
// R9/R10 lesson: kernel needs ~230 total regs; any launch_bounds cap below
//   that spills accumulators to scratch (R10: 512MB traffic). Stable point
//   is 2 waves/SIMD. So: raise MFMA density per iteration + cut VALU.
// R11: (1) acc[4][7] x 2 passes, spill-safe: all epilogues finish before
//   phase2 (acc dead before acc2 lives), smH 8 slots (58KB LDS, 2 blk/CU),
//   cap (256,2). 28 MFMA / 7 weight loads, 4 barriers/block total.
//   (2) fp16 everywhere (v_pk_mul_f16 for the pair product: 4 packed muls
//   vs 8 mulpack*3; 1-op cvt packs; same MFMA rate; better precision).
//   (3) b2/W3 hoisted out of phase-3 loops.
// R11b: fix cvt_pkrtz type (__fp16 vector union).
// ---------------------------------------------------------------------------

#define NB 4
#define NN 256
#define DD 768
#define TT 4096
#define HP 224
#define NTILES 14
#define KT1 24
#define KT2 7
#define TRI 136
#define ABS 448          // AB row stride (fp16): [A(224) | B(224)]
#define MTS 3584         // shorts per packed Mtile (16 rows x 224)

typedef _Float16 f16x8 __attribute__((ext_vector_type(8)));
typedef _Float16 f16x2 __attribute__((ext_vector_type(2)));
typedef __fp16 fp16x2 __attribute__((ext_vector_type(2)));
typedef __attribute__((ext_vector_type(4))) float f32x4;

union FragU { uint4 u; f16x8 h; };
union H2U { unsigned int u; f16x2 h; };
union PKU { unsigned int u; fp16x2 h; };

__device__ __forceinline__ unsigned int h2mul(unsigned int a, unsigned int b) {
    H2U x, y, r; x.u = a; y.u = b; r.h = x.h * y.h;   // v_pk_mul_f16
    return r.u;
}
__device__ __forceinline__ float hlo(unsigned int v) { H2U x; x.u = v; return (float)x.h[0]; }
__device__ __forceinline__ float hhi(unsigned int v) { H2U x; x.u = v; return (float)x.h[1]; }
__device__ __forceinline__ unsigned short f2h(float f) {   // RNE v_cvt_f16_f32
    _Float16 h = (_Float16)f;
    union { _Float16 h; unsigned short u; } r; r.h = h; return r.u;
}
__device__ __forceinline__ float h2f(unsigned short u) {
    union { unsigned short u; _Float16 h; } r; r.u = u; return (float)r.h;
}
__device__ __forceinline__ unsigned int pk2(float lo, float hi) {  // packed RTZ
    PKU r; r.h = __builtin_amdgcn_cvt_pkrtz(lo, hi); return r.u;
}

// ---------------------------------------------------------------------------
// K0 (merged): weight swizzle (blocks 0..2211) + gather/cast (blocks 2212..3235)
//   frag layout: buf[((kt*NT+nt)*64+lane)*8+j] = W[kt*32+(lane>>4)*8+j][nt*16+(lane&15)]
//   All outputs fp16 now.
// ---------------------------------------------------------------------------
__global__ void prep_all(const float* __restrict__ W1, const float* __restrict__ W2,
                         const float* __restrict__ ee, const int* __restrict__ eidx,
                         unsigned short* __restrict__ w1n,
                         unsigned short* __restrict__ w1s,
                         unsigned short* __restrict__ w2s,
                         unsigned short* __restrict__ emb) {
    const int N1n = 24 * 28 * 512;   // 344064
    const int N1s = 24 * 14 * 512;   // 172032
    const int N2  = 7 * 14 * 512;    // 50176
    int bx = blockIdx.x;
    if (bx >= 2212) {                 // gather + fp32->fp16
        int g = bx - 2212;
        int b = g >> 8, n = g & 255;
        int t = eidx[b * NN + n];
        const float* src = ee + ((size_t)b * TT + t) * DD;
        unsigned short* dst = emb + ((size_t)b * NN + n) * DD;
        for (int e = threadIdx.x; e < DD; e += 256) dst[e] = f2h(src[e]);
        return;
    }
    int idx = bx * 256 + threadIdx.x;
    if (idx < N1n) {
        int j = idx & 7, lane = (idx >> 3) & 63, f = idx >> 9;
        int nt = f % 28, kt = f / 28;
        int k = kt * 32 + (lane >> 4) * 8 + j;     // 0..767
        int n = nt * 16 + (lane & 15);             // 0..447
        float v;
        if (n < HP) v = (n < 200) ? W1[(size_t)k * 200 + n] : 0.f;
        else { int c2 = n - HP; v = (c2 < 200) ? W1[(size_t)(768 + k) * 200 + c2] : 0.f; }
        w1n[idx] = f2h(v);
    } else if (idx < N1n + N1s) {
        int i2 = idx - N1n;
        int j = i2 & 7, lane = (i2 >> 3) & 63, f = i2 >> 9;
        int nt = f % NTILES, kt = f / NTILES;
        int k = kt * 32 + (lane >> 4) * 8 + j;
        int n = nt * 16 + (lane & 15);
        float v = (n < 200) ? W1[(size_t)(1536 + k) * 200 + n] : 0.f;
        w1s[i2] = f2h(v);
    } else if (idx < N1n + N1s + N2) {
        int i2 = idx - N1n - N1s;
        int j = i2 & 7, lane = (i2 >> 3) & 63, f = i2 >> 9;
        int nt = f % NTILES, kt = f / NTILES;
        int k = kt * 32 + (lane >> 4) * 8 + j;
        int n = nt * 16 + (lane & 15);
        float v = (k < 200 && n < 200) ? W2[(size_t)k * 200 + n] : 0.f;
        w2s[i2] = f2h(v);
    }
}

// ---------------------------------------------------------------------------
// K2: AB = emb(1024x768) @ [W1top|W1mid](768x448), fp16 MFMA, fp16 out.
//   256 one-wave blocks (mtile 0..63 x ngroup 0..3) -> all CUs busy.
// ---------------------------------------------------------------------------
__global__ __launch_bounds__(64)
void node_mfma(const unsigned short* __restrict__ emb,
               const unsigned short* __restrict__ w1n,
               unsigned short* __restrict__ AB) {
    int lane = threadIdx.x & 63;
    int q = lane >> 4, c = lane & 15;
    int mt = blockIdx.x >> 2;         // 0..63
    int ng = blockIdx.x & 3;          // 0..3
    int m0 = mt * 16;
    const uint4* ga = (const uint4*)emb + (size_t)(m0 + c) * 96;
    const uint4* gb = (const uint4*)w1n;

    f32x4 acc[7];
#pragma unroll
    for (int n = 0; n < 7; ++n) acc[n] = (f32x4){0.f, 0.f, 0.f, 0.f};

    for (int kt = 0; kt < KT1; ++kt) {
        FragU a; a.u = ga[kt * 4 + q];
#pragma unroll
        for (int n = 0; n < 7; ++n) {
            FragU bb; bb.u = gb[((kt * 28 + ng * 7 + n) << 6) + lane];
            acc[n] = __builtin_amdgcn_mfma_f32_16x16x32_f16(a.h, bb.h, acc[n], 0, 0, 0);
        }
    }
#pragma unroll
    for (int n = 0; n < 7; ++n) {
        int col = (ng * 7 + n) * 16 + c;
#pragma unroll
        for (int rr = 0; rr < 4; ++rr)
            AB[(size_t)(m0 + q * 4 + rr) * ABS + col] = f2h(acc[n][rr]);
    }
}

// ---------------------------------------------------------------------------
// K3: fused pair MLP per 16x16 (i,j) tile. 256 threads = 4 waves.
//   2 passes of 8 i-rows. Wave (mp = w>>1, nh = w&1) owns i-rows
//   pass*8 + mp*4 + t (t=0..3), ntile-half nh; acc[4][7].
//   phase1: no barriers, weights from global (L2), A-frag = pk_mul(ei,ej).
//   epilogue: ALL 4 Mtiles -> smH (8 slots) -> B1 -> phase2 acc2[4][7]
//   (acc dead before acc2 lives: no AGPR overlap) -> phase3 -> B2 -> store.
// ---------------------------------------------------------------------------
__global__ __launch_bounds__(256, 2)
void pair_mlp(
    const unsigned short* __restrict__ emb,
    const unsigned short* __restrict__ w1s,
    const unsigned short* __restrict__ w2s,
    const unsigned short* __restrict__ AB,
    const float* __restrict__ b1, const float* __restrict__ b2,
    const float* __restrict__ W3, const float* __restrict__ b3,
    float* __restrict__ S) {
    int z = blockIdx.x;
    int b = z / TRI;
    int r = z % TRI;
    int ti = (int)((sqrtf(8.f * (float)r + 1.f) - 1.f) * 0.5f);
    while ((ti + 1) * (ti + 2) / 2 <= r) ++ti;
    while (ti * (ti + 1) / 2 > r) --ti;
    int tj = r - ti * (ti + 1) / 2;
    int i0 = ti << 4, j0 = tj << 4;

    int tid = threadIdx.x;
    int lane = tid & 63;
    int w = tid >> 6;                 // 0..3
    int q = lane >> 4, c = lane & 15;
    int mp = w >> 1, nh = w & 1;

    __shared__ __align__(16) unsigned short smH[8 * MTS];    // 57344 B h1 (8 slots)
    __shared__ float sred[2][128];                           //  1024 B

    const uint4* w1f = (const uint4*)w1s;
    const uint4* w2f = (const uint4*)w2s;
    const uint4* gI  = (const uint4*)(emb + ((size_t)b * NN + i0) * DD);
    const uint4* gJc = (const uint4*)(emb + ((size_t)b * NN + j0 + c) * DD); // per-lane row

    // hoisted phase-3 constants (per nh,c)
    float b2v[7], w3v[7];
#pragma unroll
    for (int n = 0; n < 7; ++n) {
        int h = ((nh * 7 + n) << 4) + c;
        b2v[n] = (h < 200) ? b2[h] : 0.f;
        w3v[n] = (h < 200) ? W3[h] : 0.f;
    }

    for (int pass = 0; pass < 2; ++pass) {
        // ---- phase 1: acc[4][7] over K=768, weights from global ----
        f32x4 acc[4][7];
#pragma unroll
        for (int t = 0; t < 4; ++t)
#pragma unroll
            for (int n = 0; n < 7; ++n)
                acc[t][n] = (f32x4){0.f, 0.f, 0.f, 0.f};

        for (int kt = 0; kt < KT1; ++kt) {
            uint4 bfr[7];
#pragma unroll
            for (int n = 0; n < 7; ++n)
                bfr[n] = w1f[(kt * NTILES + nh * 7 + n) * 64 + lane];
            uint4 ej = gJc[kt * 4 + q];
#pragma unroll
            for (int t = 0; t < 4; ++t) {
                uint4 ei = gI[(pass * 8 + mp * 4 + t) * 96 + kt * 4 + q]; // quad-broadcast
                FragU a;
                a.u.x = h2mul(ei.x, ej.x);
                a.u.y = h2mul(ei.y, ej.y);
                a.u.z = h2mul(ei.z, ej.z);
                a.u.w = h2mul(ei.w, ej.w);
#pragma unroll
                for (int n = 0; n < 7; ++n) {
                    FragU bb; bb.u = bfr[n];
                    acc[t][n] = __builtin_amdgcn_mfma_f32_16x16x32_f16(a.h, bb.h, acc[t][n], 0, 0, 0);
                }
            }
        }

        // ---- Ai / Bv(+b1) packed fp16 regs (transient; AB rows L1/L2-hot) ----
        unsigned int aiP[2][7];
#pragma unroll
        for (int g2 = 0; g2 < 2; ++g2)
#pragma unroll
            for (int n = 0; n < 7; ++n) {
                int h = ((nh * 7 + n) << 4) + c;
                size_t rowL = (size_t)(b * NN + i0 + pass * 8 + mp * 4 + 2 * g2);
                aiP[g2][n] = ((unsigned int)AB[(rowL + 1) * ABS + h] << 16) |
                             (unsigned int)AB[rowL * ABS + h];
            }
        unsigned int bvP[2][7];
#pragma unroll
        for (int rp = 0; rp < 2; ++rp)
#pragma unroll
            for (int n = 0; n < 7; ++n) {
                int h = ((nh * 7 + n) << 4) + c;
                float bb1 = (h < 200) ? b1[h] : 0.f;
                float lo = h2f(AB[(size_t)(b * NN + j0 + q * 4 + 2 * rp) * ABS + HP + h]) + bb1;
                float hi = h2f(AB[(size_t)(b * NN + j0 + q * 4 + 2 * rp + 1) * ABS + HP + h]) + bb1;
                bvP[rp][n] = pk2(lo, hi);
            }

        // ---- epilogue (ALL 4 Mtiles): h1 = relu(acc + Ai + Bv) -> smH ----
#pragma unroll
        for (int t = 0; t < 4; ++t) {
            int lt = mp * 4 + t;
#pragma unroll
            for (int n = 0; n < 7; ++n) {
                int h = ((nh * 7 + n) << 4) + c;
                float aif = (t & 1) ? hhi(aiP[t >> 1][n]) : hlo(aiP[t >> 1][n]);
                int kk2 = h >> 5, q2 = (h >> 3) & 3, j2 = h & 7;
                int fa = lt * MTS + ((kk2 * 4 + q2) << 7) + j2;
#pragma unroll
                for (int rr = 0; rr < 4; ++rr) {
                    float bvf = (rr & 1) ? hhi(bvP[rr >> 1][n]) : hlo(bvP[rr >> 1][n]);
                    float v = acc[t][n][rr] + aif + bvf;
                    v = fmaxf(v, 0.f);
                    smH[fa + ((q * 4 + rr) << 3)] = f2h(v);
                }
            }
        }
        __syncthreads();   // B1: smH (all 8 slots) written -> phase2 may read

        // ---- phase 2: acc2[4][7] over K=224 (acc is dead; AGPRs reused) ----
        f32x4 acc2[4][7];
#pragma unroll
        for (int u = 0; u < 4; ++u)
#pragma unroll
            for (int n = 0; n < 7; ++n)
                acc2[u][n] = (f32x4){0.f, 0.f, 0.f, 0.f};

        for (int kk = 0; kk < KT2; ++kk) {
            uint4 bfr2[7];
#pragma unroll
            for (int n = 0; n < 7; ++n)
                bfr2[n] = w2f[(kk * NTILES + nh * 7 + n) * 64 + lane];
#pragma unroll
            for (int u = 0; u < 4; ++u) {
                int lt = mp * 4 + u;
                FragU a2;
                a2.u = *(const uint4*)(&smH[lt * MTS + (((kk * 4 + q) * 16 + c) << 3)]);
#pragma unroll
                for (int n = 0; n < 7; ++n) {
                    FragU bb; bb.u = bfr2[n];
                    acc2[u][n] = __builtin_amdgcn_mfma_f32_16x16x32_f16(a2.h, bb.h, acc2[u][n], 0, 0, 0);
                }
            }
        }

        // ---- phase 3: s = relu(h2 + b2) . W3, reduce cols via shfl ----
#pragma unroll
        for (int u = 0; u < 4; ++u) {
#pragma unroll
            for (int rr = 0; rr < 4; ++rr) {
                float part = 0.f;
#pragma unroll
                for (int n = 0; n < 7; ++n) {
                    float hv = fmaxf(acc2[u][n][rr] + b2v[n], 0.f);
                    part += hv * w3v[n];
                }
                part += __shfl_xor(part, 1);
                part += __shfl_xor(part, 2);
                part += __shfl_xor(part, 4);
                part += __shfl_xor(part, 8);
                if (c == 0)
                    sred[nh][((mp * 4 + u) << 4) + q * 4 + rr] = part;
            }
        }
        __syncthreads();   // B2: sred written -> store; fences smH reuse

        // ---- store this pass's 128 pairs ----
        if (tid < 128) {
            int slot = tid >> 4;
            int i = i0 + pass * 8 + slot;
            int j = j0 + (tid & 15);
            S[((size_t)b * NN + i) * NN + j] = sred[0][tid] + sred[1][tid] + b3[0];
        }
        // sred WAR vs next pass's phase3 is separated by next pass's B1
    }
}

// ---------------------------------------------------------------------------
// K4: masked softmax per row; diag logit = 0; invalid -> -1000
// ---------------------------------------------------------------------------
__global__ __launch_bounds__(256) void softmax_rows(const float* __restrict__ S,
                                                    float* __restrict__ out) {
    int b = blockIdx.x >> 8, i = blockIdx.x & 255;
    int j = threadIdx.x;
    int lane = j & 63, w = j >> 6;
    __shared__ float red[16];
    float x = (j < i) ? S[((size_t)b * NN + i) * NN + j] : ((j == i) ? 0.f : -1e30f);
    float m = x;
#pragma unroll
    for (int off = 32; off; off >>= 1) m = fmaxf(m, __shfl_xor(m, off));
    if (lane == 0) red[w] = m;
    __syncthreads();
    float mx = fmaxf(fmaxf(red[0], red[1]), fmaxf(red[2], red[3]));
    float e = (j <= i) ? __expf(x - mx) : 0.f;
    float s = e;
#pragma unroll
    for (int off = 32; off; off >>= 1) s += __shfl_xor(s, off);
    if (lane == 0) red[8 + w] = s;
    __syncthreads();
    float sum = red[8] + red[9] + red[10] + red[11];
    out[((size_t)b * NN + i) * NN + j] = (j <= i) ? (e / sum) : -1000.0f;
}

// ---------------------------------------------------------------------------
extern "C" void kernel_launch(void* const* d_in, const int* in_sizes, int n_in,
                              void* d_out, int out_size, void* d_ws, size_t ws_size,
                              hipStream_t stream) {
    const float* ee  = (const float*)d_in[0];
    const int*   eidx = (const int*)d_in[1];
    const float* W1  = (const float*)d_in[2];
    const float* b1  = (const float*)d_in[3];
    const float* W2  = (const float*)d_in[4];
    const float* b2  = (const float*)d_in[5];
    const float* W3  = (const float*)d_in[6];
    const float* b3  = (const float*)d_in[7];
    float* out = (float*)d_out;

    char* p = (char*)d_ws;
    unsigned short* emb = (unsigned short*)p; p += (size_t)NB * NN * DD * 2;       // 1.5 MB
    unsigned short* w1n = (unsigned short*)p; p += (size_t)24 * 28 * 512 * 2;      // 672 KB
    unsigned short* w1s = (unsigned short*)p; p += (size_t)24 * 14 * 512 * 2;      // 336 KB
    unsigned short* w2s = (unsigned short*)p; p += (size_t)7 * 14 * 512 * 2;       // 98 KB
    unsigned short* AB  = (unsigned short*)p; p += (size_t)NB * NN * ABS * 2;      // 896 KB
    float* S  = (float*)p; p += (size_t)NB * NN * NN * 4;                           // 1 MB

    prep_all<<<3236, 256, 0, stream>>>(W1, W2, ee, eidx, w1n, w1s, w2s, emb);
    node_mfma<<<256, 64, 0, stream>>>(emb, w1n, AB);
    pair_mlp<<<NB * TRI, 256, 0, stream>>>(emb, w1s, w2s, AB, b1, b2, W3, b3, S);
    softmax_rows<<<NB * NN, 256, 0, stream>>>(S, out);
}

// Round 6
// 288.629 us; speedup vs baseline: 1.3455x; 1.1623x over previous
//
#include <hip/hip_runtime.h>

// ---------------------------------------------------------------------------
// CorefPairScorer: B=4, T=4096, D=768, N=256, HID=200 (padded to 224)
// h1(i,j) = relu(A[i] + Bv[j] + (emb_i*emb_j)@W1bot + b1)
// h2 = relu(h1@W2 + b2); s = h2@W3 + b3; masked softmax rows.
// R7-R11 invariant: 4-wave barrier-coupled blocks at 2 blk/CU => 210-230us
//   regardless of inner loop (DMA weights, density, fp16 all neutral);
//   112-reg accumulators spill whenever compiler unrolls (R9/R10/R11).
// R12: ZERO-BARRIER redesign. One wave owns {2 i-rows x all 14 ntiles} of a
//   16x16 (i,j) tile => h1 is wave-local; h1->phase2 transpose through a
//   wave-PRIVATE LDS slot needs only s_waitcnt lgkmcnt(0), no __syncthreads.
//   Grid 1088 blocks x 4 independent waves (4352 waves). acc[2][14] in
//   AGPRs; #pragma unroll 1 on K loops + 7-at-a-time fragment loads to stop
//   unroll-driven spill. Tile-mates 544 apart in blockIdx => same XCD L2.
// ---------------------------------------------------------------------------

#define NB 4
#define NN 256
#define DD 768
#define TT 4096
#define HP 224
#define NTILES 14
#define KT1 24
#define KT2 7
#define TRI 136
#define ABS 448          // AB row stride (fp16): [A(224) | B(224)]
#define MTS 3584         // shorts per packed Mtile (16 rows x 224)

typedef _Float16 f16x8 __attribute__((ext_vector_type(8)));
typedef _Float16 f16x2 __attribute__((ext_vector_type(2)));
typedef __fp16 fp16x2 __attribute__((ext_vector_type(2)));
typedef __attribute__((ext_vector_type(4))) float f32x4;

union FragU { uint4 u; f16x8 h; };
union H2U { unsigned int u; f16x2 h; };

__device__ __forceinline__ unsigned int h2mul(unsigned int a, unsigned int b) {
    H2U x, y, r; x.u = a; y.u = b; r.h = x.h * y.h;   // v_pk_mul_f16
    return r.u;
}
__device__ __forceinline__ float hlo(unsigned int v) { H2U x; x.u = v; return (float)x.h[0]; }
__device__ __forceinline__ float hhi(unsigned int v) { H2U x; x.u = v; return (float)x.h[1]; }
__device__ __forceinline__ unsigned short f2h(float f) {
    _Float16 h = (_Float16)f;
    union { _Float16 h; unsigned short u; } r; r.h = h; return r.u;
}
__device__ __forceinline__ float h2f(unsigned short u) {
    union { unsigned short u; _Float16 h; } r; r.u = u; return (float)r.h;
}

// ---------------------------------------------------------------------------
// K0 (merged): weight swizzle (blocks 0..2211) + gather/cast (blocks 2212..3235)
//   frag layout: buf[((kt*NT+nt)*64+lane)*8+j] = W[kt*32+(lane>>4)*8+j][nt*16+(lane&15)]
// ---------------------------------------------------------------------------
__global__ void prep_all(const float* __restrict__ W1, const float* __restrict__ W2,
                         const float* __restrict__ ee, const int* __restrict__ eidx,
                         unsigned short* __restrict__ w1n,
                         unsigned short* __restrict__ w1s,
                         unsigned short* __restrict__ w2s,
                         unsigned short* __restrict__ emb) {
    const int N1n = 24 * 28 * 512;   // 344064
    const int N1s = 24 * 14 * 512;   // 172032
    const int N2  = 7 * 14 * 512;    // 50176
    int bx = blockIdx.x;
    if (bx >= 2212) {                 // gather + fp32->fp16
        int g = bx - 2212;
        int b = g >> 8, n = g & 255;
        int t = eidx[b * NN + n];
        const float* src = ee + ((size_t)b * TT + t) * DD;
        unsigned short* dst = emb + ((size_t)b * NN + n) * DD;
        for (int e = threadIdx.x; e < DD; e += 256) dst[e] = f2h(src[e]);
        return;
    }
    int idx = bx * 256 + threadIdx.x;
    if (idx < N1n) {
        int j = idx & 7, lane = (idx >> 3) & 63, f = idx >> 9;
        int nt = f % 28, kt = f / 28;
        int k = kt * 32 + (lane >> 4) * 8 + j;     // 0..767
        int n = nt * 16 + (lane & 15);             // 0..447
        float v;
        if (n < HP) v = (n < 200) ? W1[(size_t)k * 200 + n] : 0.f;
        else { int c2 = n - HP; v = (c2 < 200) ? W1[(size_t)(768 + k) * 200 + c2] : 0.f; }
        w1n[idx] = f2h(v);
    } else if (idx < N1n + N1s) {
        int i2 = idx - N1n;
        int j = i2 & 7, lane = (i2 >> 3) & 63, f = i2 >> 9;
        int nt = f % NTILES, kt = f / NTILES;
        int k = kt * 32 + (lane >> 4) * 8 + j;
        int n = nt * 16 + (lane & 15);
        float v = (n < 200) ? W1[(size_t)(1536 + k) * 200 + n] : 0.f;
        w1s[i2] = f2h(v);
    } else if (idx < N1n + N1s + N2) {
        int i2 = idx - N1n - N1s;
        int j = i2 & 7, lane = (i2 >> 3) & 63, f = i2 >> 9;
        int nt = f % NTILES, kt = f / NTILES;
        int k = kt * 32 + (lane >> 4) * 8 + j;
        int n = nt * 16 + (lane & 15);
        float v = (k < 200 && n < 200) ? W2[(size_t)k * 200 + n] : 0.f;
        w2s[i2] = f2h(v);
    }
}

// ---------------------------------------------------------------------------
// K2: AB = emb(1024x768) @ [W1top|W1mid](768x448), fp16 MFMA, fp16 out.
//   256 one-wave blocks (mtile 0..63 x ngroup 0..3) -> all CUs busy.
// ---------------------------------------------------------------------------
__global__ __launch_bounds__(64)
void node_mfma(const unsigned short* __restrict__ emb,
               const unsigned short* __restrict__ w1n,
               unsigned short* __restrict__ AB) {
    int lane = threadIdx.x & 63;
    int q = lane >> 4, c = lane & 15;
    int mt = blockIdx.x >> 2;         // 0..63
    int ng = blockIdx.x & 3;          // 0..3
    int m0 = mt * 16;
    const uint4* ga = (const uint4*)emb + (size_t)(m0 + c) * 96;
    const uint4* gb = (const uint4*)w1n;

    f32x4 acc[7];
#pragma unroll
    for (int n = 0; n < 7; ++n) acc[n] = (f32x4){0.f, 0.f, 0.f, 0.f};

    for (int kt = 0; kt < KT1; ++kt) {
        FragU a; a.u = ga[kt * 4 + q];
#pragma unroll
        for (int n = 0; n < 7; ++n) {
            FragU bb; bb.u = gb[((kt * 28 + ng * 7 + n) << 6) + lane];
            acc[n] = __builtin_amdgcn_mfma_f32_16x16x32_f16(a.h, bb.h, acc[n], 0, 0, 0);
        }
    }
#pragma unroll
    for (int n = 0; n < 7; ++n) {
        int col = (ng * 7 + n) * 16 + c;
#pragma unroll
        for (int rr = 0; rr < 4; ++rr)
            AB[(size_t)(m0 + q * 4 + rr) * ABS + col] = f2h(acc[n][rr]);
    }
}

// ---------------------------------------------------------------------------
// K3: pair MLP, zero-barrier. Each WAVE owns (tile, i-row-pair irp):
//   i-rows {i0+2*irp, i0+2*irp+1}, all 16 jj, all 224 h-cols.
//   phase1: acc[2][14] over K=768 (A-frag = pk_mul(ei_t, ej), per-lane jj=c);
//   epilogue: h1 -> wave-PRIVATE LDS slots (frag-packed);
//   s_waitcnt lgkmcnt(0); phase2: acc2[2][14] over K=224;
//   phase3: dot W3, shfl-reduce over c, float4 store. No __syncthreads.
// Block = 4 independent waves. Grid 1088 = 2 x 544 (tile-mates same XCD).
// ---------------------------------------------------------------------------
__global__ __launch_bounds__(256)
void pair_wave(
    const unsigned short* __restrict__ emb,
    const unsigned short* __restrict__ w1s,
    const unsigned short* __restrict__ w2s,
    const unsigned short* __restrict__ AB,
    const float* __restrict__ b1, const float* __restrict__ b2,
    const float* __restrict__ W3, const float* __restrict__ b3,
    float* __restrict__ S) {
    int bid = blockIdx.x;
    int m = bid / 544;                // 0..1 : which i-row-pair group
    int g = bid % 544;                // tile id; mates differ by 544 = 0 mod 8
    int b = g / TRI;
    int r = g % TRI;
    int ti = (int)((sqrtf(8.f * (float)r + 1.f) - 1.f) * 0.5f);
    while ((ti + 1) * (ti + 2) / 2 <= r) ++ti;
    while (ti * (ti + 1) / 2 > r) --ti;
    int tj = r - ti * (ti + 1) / 2;
    int i0 = ti << 4, j0 = tj << 4;

    int tid = threadIdx.x;
    int lane = tid & 63;
    int w = tid >> 6;                 // 0..3
    int q = lane >> 4, c = lane & 15;
    int irp = m * 4 + w;              // 0..7
    int iA = i0 + irp * 2, iB = iA + 1;

    __shared__ __align__(16) unsigned short smH[4 * 2 * MTS];   // 57344 B
    unsigned short* slot0 = &smH[(w * 2 + 0) * MTS];
    unsigned short* slot1 = &smH[(w * 2 + 1) * MTS];

    const uint4* w1f = (const uint4*)w1s;
    const uint4* w2f = (const uint4*)w2s;
    const uint4* gI0 = (const uint4*)(emb + ((size_t)b * NN + iA) * DD);
    const uint4* gI1 = (const uint4*)(emb + ((size_t)b * NN + iB) * DD);
    const uint4* gJc = (const uint4*)(emb + ((size_t)b * NN + j0 + c) * DD);

    // ---- phase 1: acc[2][14] over K=768 ----
    f32x4 acc[2][14];
#pragma unroll
    for (int t = 0; t < 2; ++t)
#pragma unroll
        for (int n = 0; n < 14; ++n)
            acc[t][n] = (f32x4){0.f, 0.f, 0.f, 0.f};

#pragma unroll 1
    for (int kt = 0; kt < KT1; ++kt) {
        uint4 ej = gJc[kt * 4 + q];               // row j0+c, k-slice
        uint4 e0 = gI0[kt * 4 + q];               // row iA (quad-broadcast)
        uint4 e1 = gI1[kt * 4 + q];               // row iB
        FragU a0, a1;
        a0.u.x = h2mul(e0.x, ej.x); a0.u.y = h2mul(e0.y, ej.y);
        a0.u.z = h2mul(e0.z, ej.z); a0.u.w = h2mul(e0.w, ej.w);
        a1.u.x = h2mul(e1.x, ej.x); a1.u.y = h2mul(e1.y, ej.y);
        a1.u.z = h2mul(e1.z, ej.z); a1.u.w = h2mul(e1.w, ej.w);
#pragma unroll
        for (int half = 0; half < 2; ++half) {
            uint4 bfr[7];
#pragma unroll
            for (int n = 0; n < 7; ++n)
                bfr[n] = w1f[(kt * NTILES + half * 7 + n) * 64 + lane];
#pragma unroll
            for (int n = 0; n < 7; ++n) {
                FragU bb; bb.u = bfr[n];
                acc[0][half * 7 + n] = __builtin_amdgcn_mfma_f32_16x16x32_f16(a0.h, bb.h, acc[0][half * 7 + n], 0, 0, 0);
                acc[1][half * 7 + n] = __builtin_amdgcn_mfma_f32_16x16x32_f16(a1.h, bb.h, acc[1][half * 7 + n], 0, 0, 0);
            }
        }
    }

    // ---- epilogue: h1 = relu(acc + A[i] + Bv[j] + b1) -> private slots ----
    {
        // af[t][n] = A[i_t][h] + b1[h]; bvp[n][p] packs Bv rows (j0+q*4+2p, +2p+1)
        float af0[14], af1[14];
        unsigned int bvp[14][2];
#pragma unroll
        for (int n = 0; n < 14; ++n) {
            int h = (n << 4) + c;
            float b1v = (h < 200) ? b1[h] : 0.f;
            af0[n] = h2f(AB[((size_t)b * NN + iA) * ABS + h]) + b1v;
            af1[n] = h2f(AB[((size_t)b * NN + iB) * ABS + h]) + b1v;
#pragma unroll
            for (int p = 0; p < 2; ++p) {
                unsigned int lo = AB[((size_t)b * NN + j0 + q * 4 + 2 * p) * ABS + HP + h];
                unsigned int hi = AB[((size_t)b * NN + j0 + q * 4 + 2 * p + 1) * ABS + HP + h];
                bvp[n][p] = (hi << 16) | lo;
            }
        }
#pragma unroll
        for (int n = 0; n < 14; ++n) {
            int h = (n << 4) + c;
            int kk2 = h >> 5, q2 = (h >> 3) & 3, j2 = h & 7;
            int fa = ((kk2 * 4 + q2) << 7) + j2;        // + jj*8 below
#pragma unroll
            for (int rr = 0; rr < 4; ++rr) {
                float bvf = (rr & 1) ? hhi(bvp[n][rr >> 1]) : hlo(bvp[n][rr >> 1]);
                int ad = fa + ((q * 4 + rr) << 3);
                slot0[ad] = f2h(fmaxf(acc[0][n][rr] + af0[n] + bvf, 0.f));
                slot1[ad] = f2h(fmaxf(acc[1][n][rr] + af1[n] + bvf, 0.f));
            }
        }
    }
    asm volatile("s_waitcnt lgkmcnt(0)" ::: "memory");   // wave-private: no barrier

    // ---- phase 2: acc2[2][14] over K=224 ----
    f32x4 acc2[2][14];
#pragma unroll
    for (int t = 0; t < 2; ++t)
#pragma unroll
        for (int n = 0; n < 14; ++n)
            acc2[t][n] = (f32x4){0.f, 0.f, 0.f, 0.f};

#pragma unroll 1
    for (int kk = 0; kk < KT2; ++kk) {
        FragU a20, a21;
        a20.u = *(const uint4*)(&slot0[(((kk * 4 + q) * 16 + c) << 3)]);
        a21.u = *(const uint4*)(&slot1[(((kk * 4 + q) * 16 + c) << 3)]);
#pragma unroll
        for (int half = 0; half < 2; ++half) {
            uint4 bfr2[7];
#pragma unroll
            for (int n = 0; n < 7; ++n)
                bfr2[n] = w2f[(kk * NTILES + half * 7 + n) * 64 + lane];
#pragma unroll
            for (int n = 0; n < 7; ++n) {
                FragU bb; bb.u = bfr2[n];
                acc2[0][half * 7 + n] = __builtin_amdgcn_mfma_f32_16x16x32_f16(a20.h, bb.h, acc2[0][half * 7 + n], 0, 0, 0);
                acc2[1][half * 7 + n] = __builtin_amdgcn_mfma_f32_16x16x32_f16(a21.h, bb.h, acc2[1][half * 7 + n], 0, 0, 0);
            }
        }
    }

    // ---- phase 3: s = relu(h2 + b2) . W3; shfl-reduce over c; float4 store ----
    {
        float b2v[14], w3v[14];
#pragma unroll
        for (int n = 0; n < 14; ++n) {
            int h = (n << 4) + c;
            b2v[n] = (h < 200) ? b2[h] : 0.f;
            w3v[n] = (h < 200) ? W3[h] : 0.f;
        }
        float bias3 = b3[0];
#pragma unroll
        for (int t = 0; t < 2; ++t) {
            float s4[4];
#pragma unroll
            for (int rr = 0; rr < 4; ++rr) {
                float part = 0.f;
#pragma unroll
                for (int n = 0; n < 14; ++n) {
                    float hv = fmaxf(acc2[t][n][rr] + b2v[n], 0.f);
                    part += hv * w3v[n];
                }
                part += __shfl_xor(part, 1);
                part += __shfl_xor(part, 2);
                part += __shfl_xor(part, 4);
                part += __shfl_xor(part, 8);
                s4[rr] = part + bias3;
            }
            if (c == 0) {
                int i = t ? iB : iA;
                float4 v4 = make_float4(s4[0], s4[1], s4[2], s4[3]);
                *(float4*)&S[((size_t)b * NN + i) * NN + j0 + q * 4] = v4;
            }
        }
    }
}

// ---------------------------------------------------------------------------
// K4: masked softmax per row; diag logit = 0; invalid -> -1000
// ---------------------------------------------------------------------------
__global__ __launch_bounds__(256) void softmax_rows(const float* __restrict__ S,
                                                    float* __restrict__ out) {
    int b = blockIdx.x >> 8, i = blockIdx.x & 255;
    int j = threadIdx.x;
    int lane = j & 63, w = j >> 6;
    __shared__ float red[16];
    float x = (j < i) ? S[((size_t)b * NN + i) * NN + j] : ((j == i) ? 0.f : -1e30f);
    float m = x;
#pragma unroll
    for (int off = 32; off; off >>= 1) m = fmaxf(m, __shfl_xor(m, off));
    if (lane == 0) red[w] = m;
    __syncthreads();
    float mx = fmaxf(fmaxf(red[0], red[1]), fmaxf(red[2], red[3]));
    float e = (j <= i) ? __expf(x - mx) : 0.f;
    float s = e;
#pragma unroll
    for (int off = 32; off; off >>= 1) s += __shfl_xor(s, off);
    if (lane == 0) red[8 + w] = s;
    __syncthreads();
    float sum = red[8] + red[9] + red[10] + red[11];
    out[((size_t)b * NN + i) * NN + j] = (j <= i) ? (e / sum) : -1000.0f;
}

// ---------------------------------------------------------------------------
extern "C" void kernel_launch(void* const* d_in, const int* in_sizes, int n_in,
                              void* d_out, int out_size, void* d_ws, size_t ws_size,
                              hipStream_t stream) {
    const float* ee  = (const float*)d_in[0];
    const int*   eidx = (const int*)d_in[1];
    const float* W1  = (const float*)d_in[2];
    const float* b1  = (const float*)d_in[3];
    const float* W2  = (const float*)d_in[4];
    const float* b2  = (const float*)d_in[5];
    const float* W3  = (const float*)d_in[6];
    const float* b3  = (const float*)d_in[7];
    float* out = (float*)d_out;

    char* p = (char*)d_ws;
    unsigned short* emb = (unsigned short*)p; p += (size_t)NB * NN * DD * 2;       // 1.5 MB
    unsigned short* w1n = (unsigned short*)p; p += (size_t)24 * 28 * 512 * 2;      // 672 KB
    unsigned short* w1s = (unsigned short*)p; p += (size_t)24 * 14 * 512 * 2;      // 336 KB
    unsigned short* w2s = (unsigned short*)p; p += (size_t)7 * 14 * 512 * 2;       // 98 KB
    unsigned short* AB  = (unsigned short*)p; p += (size_t)NB * NN * ABS * 2;      // 896 KB
    float* S  = (float*)p; p += (size_t)NB * NN * NN * 4;                           // 1 MB

    prep_all<<<3236, 256, 0, stream>>>(W1, W2, ee, eidx, w1n, w1s, w2s, emb);
    node_mfma<<<256, 64, 0, stream>>>(emb, w1n, AB);
    pair_wave<<<1088, 256, 0, stream>>>(emb, w1s, w2s, AB, b1, b2, W3, b3, S);
    softmax_rows<<<NB * NN, 256, 0, stream>>>(S, out);
}

// Round 7
// 248.525 us; speedup vs baseline: 1.5627x; 1.1614x over previous
//
#include <hip/hip_runtime.h>

// ---------------------------------------------------------------------------
// CorefPairScorer: B=4, T=4096, D=768, N=256, HID=200 (padded to 224)
// h1(i,j) = relu(A[i] + Bv[j] + (emb_i*emb_j)@W1bot + b1)
// h2 = relu(h1@W2 + b2); s = h2@W3 + b3; masked softmax rows.
// R12 (zero-barrier, acc[2][14]): 184us, no spill, but VGPR 172 total (gfx950
//   UNIFIED VGPR/AGPR file!) -> 2 waves/SIMD (3x172=516>512). Latency-bound
//   on 14 weight-frag L2 loads/iter at 31% of per-CU L2 BW.
// R13: halve per-wave regs to double concurrency. Wave owns 2 i-rows x one
//   ntile-HALF: acc[2][7]=56 acc regs, target total <=128 via
//   __launch_bounds__(128,4) -> 4 waves/SIMD. Block = 128 thr = the nh pair,
//   coupled only by 2 cheap 2-wave barriers (h1 exchange, sred combine).
//   LDS 14.6KB/block. Grid 4352 blocks (544 tiles x 8 row-pairs; tile mates
//   544 apart = same XCD mod 8).
// ---------------------------------------------------------------------------

#define NB 4
#define NN 256
#define DD 768
#define TT 4096
#define HP 224
#define NTILES 14
#define KT1 24
#define KT2 7
#define TRI 136
#define ABS 448          // AB row stride (fp16): [A(224) | B(224)]
#define MTS 3584         // shorts per packed Mtile (16 rows x 224)

typedef _Float16 f16x8 __attribute__((ext_vector_type(8)));
typedef _Float16 f16x2 __attribute__((ext_vector_type(2)));
typedef __attribute__((ext_vector_type(4))) float f32x4;

union FragU { uint4 u; f16x8 h; };
union H2U { unsigned int u; f16x2 h; };

__device__ __forceinline__ unsigned int h2mul(unsigned int a, unsigned int b) {
    H2U x, y, r; x.u = a; y.u = b; r.h = x.h * y.h;   // v_pk_mul_f16
    return r.u;
}
__device__ __forceinline__ float hlo(unsigned int v) { H2U x; x.u = v; return (float)x.h[0]; }
__device__ __forceinline__ float hhi(unsigned int v) { H2U x; x.u = v; return (float)x.h[1]; }
__device__ __forceinline__ unsigned short f2h(float f) {
    _Float16 h = (_Float16)f;
    union { _Float16 h; unsigned short u; } r; r.h = h; return r.u;
}
__device__ __forceinline__ float h2f(unsigned short u) {
    union { unsigned short u; _Float16 h; } r; r.u = u; return (float)r.h;
}

// ---------------------------------------------------------------------------
// K0 (merged): weight swizzle (blocks 0..2211) + gather/cast (blocks 2212..3235)
//   frag layout: buf[((kt*NT+nt)*64+lane)*8+j] = W[kt*32+(lane>>4)*8+j][nt*16+(lane&15)]
// ---------------------------------------------------------------------------
__global__ void prep_all(const float* __restrict__ W1, const float* __restrict__ W2,
                         const float* __restrict__ ee, const int* __restrict__ eidx,
                         unsigned short* __restrict__ w1n,
                         unsigned short* __restrict__ w1s,
                         unsigned short* __restrict__ w2s,
                         unsigned short* __restrict__ emb) {
    const int N1n = 24 * 28 * 512;   // 344064
    const int N1s = 24 * 14 * 512;   // 172032
    const int N2  = 7 * 14 * 512;    // 50176
    int bx = blockIdx.x;
    if (bx >= 2212) {                 // gather + fp32->fp16
        int g = bx - 2212;
        int b = g >> 8, n = g & 255;
        int t = eidx[b * NN + n];
        const float* src = ee + ((size_t)b * TT + t) * DD;
        unsigned short* dst = emb + ((size_t)b * NN + n) * DD;
        for (int e = threadIdx.x; e < DD; e += 256) dst[e] = f2h(src[e]);
        return;
    }
    int idx = bx * 256 + threadIdx.x;
    if (idx < N1n) {
        int j = idx & 7, lane = (idx >> 3) & 63, f = idx >> 9;
        int nt = f % 28, kt = f / 28;
        int k = kt * 32 + (lane >> 4) * 8 + j;     // 0..767
        int n = nt * 16 + (lane & 15);             // 0..447
        float v;
        if (n < HP) v = (n < 200) ? W1[(size_t)k * 200 + n] : 0.f;
        else { int c2 = n - HP; v = (c2 < 200) ? W1[(size_t)(768 + k) * 200 + c2] : 0.f; }
        w1n[idx] = f2h(v);
    } else if (idx < N1n + N1s) {
        int i2 = idx - N1n;
        int j = i2 & 7, lane = (i2 >> 3) & 63, f = i2 >> 9;
        int nt = f % NTILES, kt = f / NTILES;
        int k = kt * 32 + (lane >> 4) * 8 + j;
        int n = nt * 16 + (lane & 15);
        float v = (n < 200) ? W1[(size_t)(1536 + k) * 200 + n] : 0.f;
        w1s[i2] = f2h(v);
    } else if (idx < N1n + N1s + N2) {
        int i2 = idx - N1n - N1s;
        int j = i2 & 7, lane = (i2 >> 3) & 63, f = i2 >> 9;
        int nt = f % NTILES, kt = f / NTILES;
        int k = kt * 32 + (lane >> 4) * 8 + j;
        int n = nt * 16 + (lane & 15);
        float v = (k < 200 && n < 200) ? W2[(size_t)k * 200 + n] : 0.f;
        w2s[i2] = f2h(v);
    }
}

// ---------------------------------------------------------------------------
// K2: AB = emb(1024x768) @ [W1top|W1mid](768x448), fp16 MFMA, fp16 out.
//   256 one-wave blocks (mtile 0..63 x ngroup 0..3) -> all CUs busy.
// ---------------------------------------------------------------------------
__global__ __launch_bounds__(64)
void node_mfma(const unsigned short* __restrict__ emb,
               const unsigned short* __restrict__ w1n,
               unsigned short* __restrict__ AB) {
    int lane = threadIdx.x & 63;
    int q = lane >> 4, c = lane & 15;
    int mt = blockIdx.x >> 2;         // 0..63
    int ng = blockIdx.x & 3;          // 0..3
    int m0 = mt * 16;
    const uint4* ga = (const uint4*)emb + (size_t)(m0 + c) * 96;
    const uint4* gb = (const uint4*)w1n;

    f32x4 acc[7];
#pragma unroll
    for (int n = 0; n < 7; ++n) acc[n] = (f32x4){0.f, 0.f, 0.f, 0.f};

    for (int kt = 0; kt < KT1; ++kt) {
        FragU a; a.u = ga[kt * 4 + q];
#pragma unroll
        for (int n = 0; n < 7; ++n) {
            FragU bb; bb.u = gb[((kt * 28 + ng * 7 + n) << 6) + lane];
            acc[n] = __builtin_amdgcn_mfma_f32_16x16x32_f16(a.h, bb.h, acc[n], 0, 0, 0);
        }
    }
#pragma unroll
    for (int n = 0; n < 7; ++n) {
        int col = (ng * 7 + n) * 16 + c;
#pragma unroll
        for (int rr = 0; rr < 4; ++rr)
            AB[(size_t)(m0 + q * 4 + rr) * ABS + col] = f2h(acc[n][rr]);
    }
}

// ---------------------------------------------------------------------------
// K3: pair MLP. Block = 128 threads = 2 waves (the nh pair) for one
//   (tile, i-row-pair). Wave nh: rows {iA,iB}, ntile-half nh, acc[2][7].
//   phase1 -> epilogue (h1 -> smH, frag-packed; each wave writes its h-half)
//   -> B1 -> phase2 acc2[2][7] (full K=224 from smH, nh-half of h2 cols)
//   -> phase3 partial dot W3 -> sred -> B2 -> combine + store.
// ---------------------------------------------------------------------------
__global__ __launch_bounds__(128, 4)
void pair_wave(
    const unsigned short* __restrict__ emb,
    const unsigned short* __restrict__ w1s,
    const unsigned short* __restrict__ w2s,
    const unsigned short* __restrict__ AB,
    const float* __restrict__ b1, const float* __restrict__ b2,
    const float* __restrict__ W3, const float* __restrict__ b3,
    float* __restrict__ S) {
    int bid = blockIdx.x;
    int rp = bid / 544;               // 0..7 : i-row-pair within tile
    int g = bid % 544;                // tile id; mates 544 apart (544%8==0)
    int b = g / TRI;
    int r = g % TRI;
    int ti = (int)((sqrtf(8.f * (float)r + 1.f) - 1.f) * 0.5f);
    while ((ti + 1) * (ti + 2) / 2 <= r) ++ti;
    while (ti * (ti + 1) / 2 > r) --ti;
    int tj = r - ti * (ti + 1) / 2;
    int i0 = ti << 4, j0 = tj << 4;

    int tid = threadIdx.x;
    int lane = tid & 63;
    int nh = tid >> 6;                // 0..1 (ntile half)
    int q = lane >> 4, c = lane & 15;
    int iA = i0 + rp * 2, iB = iA + 1;

    __shared__ __align__(16) unsigned short smH[2 * MTS];   // 14336 B
    __shared__ float sred[2][32];                           //   256 B
    unsigned short* slot0 = smH;
    unsigned short* slot1 = smH + MTS;

    const uint4* w1f = (const uint4*)w1s;
    const uint4* w2f = (const uint4*)w2s;
    const uint4* gI0 = (const uint4*)(emb + ((size_t)b * NN + iA) * DD);
    const uint4* gI1 = (const uint4*)(emb + ((size_t)b * NN + iB) * DD);
    const uint4* gJc = (const uint4*)(emb + ((size_t)b * NN + j0 + c) * DD);

    // ---- phase 1: acc[2][7] over K=768 (nh-half of h1 cols) ----
    f32x4 acc[2][7];
#pragma unroll
    for (int t = 0; t < 2; ++t)
#pragma unroll
        for (int n = 0; n < 7; ++n)
            acc[t][n] = (f32x4){0.f, 0.f, 0.f, 0.f};

#pragma unroll 1
    for (int kt = 0; kt < KT1; ++kt) {
        uint4 bfr[7];
#pragma unroll
        for (int n = 0; n < 7; ++n)
            bfr[n] = w1f[(kt * NTILES + nh * 7 + n) * 64 + lane];
        uint4 ej = gJc[kt * 4 + q];               // row j0+c, k-slice
        uint4 e0 = gI0[kt * 4 + q];               // row iA (quad-broadcast)
        uint4 e1 = gI1[kt * 4 + q];               // row iB
        FragU a0, a1;
        a0.u.x = h2mul(e0.x, ej.x); a0.u.y = h2mul(e0.y, ej.y);
        a0.u.z = h2mul(e0.z, ej.z); a0.u.w = h2mul(e0.w, ej.w);
        a1.u.x = h2mul(e1.x, ej.x); a1.u.y = h2mul(e1.y, ej.y);
        a1.u.z = h2mul(e1.z, ej.z); a1.u.w = h2mul(e1.w, ej.w);
#pragma unroll
        for (int n = 0; n < 7; ++n) {
            FragU bb; bb.u = bfr[n];
            acc[0][n] = __builtin_amdgcn_mfma_f32_16x16x32_f16(a0.h, bb.h, acc[0][n], 0, 0, 0);
            acc[1][n] = __builtin_amdgcn_mfma_f32_16x16x32_f16(a1.h, bb.h, acc[1][n], 0, 0, 0);
        }
    }

    // ---- epilogue: h1 = relu(acc + A[i] + Bv[j] + b1) -> smH (nh half) ----
    {
        float af0[7], af1[7];
        unsigned int bvp[7][2];
#pragma unroll
        for (int n = 0; n < 7; ++n) {
            int h = ((nh * 7 + n) << 4) + c;
            float b1v = (h < 200) ? b1[h] : 0.f;
            af0[n] = h2f(AB[((size_t)b * NN + iA) * ABS + h]) + b1v;
            af1[n] = h2f(AB[((size_t)b * NN + iB) * ABS + h]) + b1v;
#pragma unroll
            for (int p = 0; p < 2; ++p) {
                unsigned int lo = AB[((size_t)b * NN + j0 + q * 4 + 2 * p) * ABS + HP + h];
                unsigned int hi = AB[((size_t)b * NN + j0 + q * 4 + 2 * p + 1) * ABS + HP + h];
                bvp[n][p] = (hi << 16) | lo;
            }
        }
#pragma unroll
        for (int n = 0; n < 7; ++n) {
            int h = ((nh * 7 + n) << 4) + c;
            int kk2 = h >> 5, q2 = (h >> 3) & 3, j2 = h & 7;
            int fa = ((kk2 * 4 + q2) << 7) + j2;        // + jj*8 below
#pragma unroll
            for (int rr = 0; rr < 4; ++rr) {
                float bvf = (rr & 1) ? hhi(bvp[n][rr >> 1]) : hlo(bvp[n][rr >> 1]);
                int ad = fa + ((q * 4 + rr) << 3);
                slot0[ad] = f2h(fmaxf(acc[0][n][rr] + af0[n] + bvf, 0.f));
                slot1[ad] = f2h(fmaxf(acc[1][n][rr] + af1[n] + bvf, 0.f));
            }
        }
    }
    __syncthreads();   // B1: both h-halves of h1 in smH

    // ---- phase 2: acc2[2][7] over K=224 (nh-half of h2 cols) ----
    f32x4 acc2[2][7];
#pragma unroll
    for (int t = 0; t < 2; ++t)
#pragma unroll
        for (int n = 0; n < 7; ++n)
            acc2[t][n] = (f32x4){0.f, 0.f, 0.f, 0.f};

#pragma unroll 1
    for (int kk = 0; kk < KT2; ++kk) {
        uint4 bfr2[7];
#pragma unroll
        for (int n = 0; n < 7; ++n)
            bfr2[n] = w2f[(kk * NTILES + nh * 7 + n) * 64 + lane];
        FragU a20, a21;
        a20.u = *(const uint4*)(&slot0[(((kk * 4 + q) * 16 + c) << 3)]);
        a21.u = *(const uint4*)(&slot1[(((kk * 4 + q) * 16 + c) << 3)]);
#pragma unroll
        for (int n = 0; n < 7; ++n) {
            FragU bb; bb.u = bfr2[n];
            acc2[0][n] = __builtin_amdgcn_mfma_f32_16x16x32_f16(a20.h, bb.h, acc2[0][n], 0, 0, 0);
            acc2[1][n] = __builtin_amdgcn_mfma_f32_16x16x32_f16(a21.h, bb.h, acc2[1][n], 0, 0, 0);
        }
    }

    // ---- phase 3: partial dot relu(h2+b2).W3 over nh half -> sred ----
    {
        float b2v[7], w3v[7];
#pragma unroll
        for (int n = 0; n < 7; ++n) {
            int h = ((nh * 7 + n) << 4) + c;
            b2v[n] = (h < 200) ? b2[h] : 0.f;
            w3v[n] = (h < 200) ? W3[h] : 0.f;
        }
#pragma unroll
        for (int t = 0; t < 2; ++t) {
#pragma unroll
            for (int rr = 0; rr < 4; ++rr) {
                float part = 0.f;
#pragma unroll
                for (int n = 0; n < 7; ++n) {
                    float hv = fmaxf(acc2[t][n][rr] + b2v[n], 0.f);
                    part += hv * w3v[n];
                }
                part += __shfl_xor(part, 1);
                part += __shfl_xor(part, 2);
                part += __shfl_xor(part, 4);
                part += __shfl_xor(part, 8);
                if (c == 0)
                    sred[nh][t * 16 + q * 4 + rr] = part;
            }
        }
    }
    __syncthreads();   // B2: both partials in sred

    if (tid < 32) {
        int t = tid >> 4, jj = tid & 15;
        float s = sred[0][tid] + sred[1][tid] + b3[0];
        S[((size_t)b * NN + iA + t) * NN + j0 + jj] = s;
    }
}

// ---------------------------------------------------------------------------
// K4: masked softmax per row; diag logit = 0; invalid -> -1000
// ---------------------------------------------------------------------------
__global__ __launch_bounds__(256) void softmax_rows(const float* __restrict__ S,
                                                    float* __restrict__ out) {
    int b = blockIdx.x >> 8, i = blockIdx.x & 255;
    int j = threadIdx.x;
    int lane = j & 63, w = j >> 6;
    __shared__ float red[16];
    float x = (j < i) ? S[((size_t)b * NN + i) * NN + j] : ((j == i) ? 0.f : -1e30f);
    float m = x;
#pragma unroll
    for (int off = 32; off; off >>= 1) m = fmaxf(m, __shfl_xor(m, off));
    if (lane == 0) red[w] = m;
    __syncthreads();
    float mx = fmaxf(fmaxf(red[0], red[1]), fmaxf(red[2], red[3]));
    float e = (j <= i) ? __expf(x - mx) : 0.f;
    float s = e;
#pragma unroll
    for (int off = 32; off; off >>= 1) s += __shfl_xor(s, off);
    if (lane == 0) red[8 + w] = s;
    __syncthreads();
    float sum = red[8] + red[9] + red[10] + red[11];
    out[((size_t)b * NN + i) * NN + j] = (j <= i) ? (e / sum) : -1000.0f;
}

// ---------------------------------------------------------------------------
extern "C" void kernel_launch(void* const* d_in, const int* in_sizes, int n_in,
                              void* d_out, int out_size, void* d_ws, size_t ws_size,
                              hipStream_t stream) {
    const float* ee  = (const float*)d_in[0];
    const int*   eidx = (const int*)d_in[1];
    const float* W1  = (const float*)d_in[2];
    const float* b1  = (const float*)d_in[3];
    const float* W2  = (const float*)d_in[4];
    const float* b2  = (const float*)d_in[5];
    const float* W3  = (const float*)d_in[6];
    const float* b3  = (const float*)d_in[7];
    float* out = (float*)d_out;

    char* p = (char*)d_ws;
    unsigned short* emb = (unsigned short*)p; p += (size_t)NB * NN * DD * 2;       // 1.5 MB
    unsigned short* w1n = (unsigned short*)p; p += (size_t)24 * 28 * 512 * 2;      // 672 KB
    unsigned short* w1s = (unsigned short*)p; p += (size_t)24 * 14 * 512 * 2;      // 336 KB
    unsigned short* w2s = (unsigned short*)p; p += (size_t)7 * 14 * 512 * 2;       // 98 KB
    unsigned short* AB  = (unsigned short*)p; p += (size_t)NB * NN * ABS * 2;      // 896 KB
    float* S  = (float*)p; p += (size_t)NB * NN * NN * 4;                           // 1 MB

    prep_all<<<3236, 256, 0, stream>>>(W1, W2, ee, eidx, w1n, w1s, w2s, emb);
    node_mfma<<<256, 64, 0, stream>>>(emb, w1n, AB);
    pair_wave<<<4352, 128, 0, stream>>>(emb, w1s, w2s, AB, b1, b2, W3, b3, S);
    softmax_rows<<<NB * NN, 256, 0, stream>>>(S, out);
}

// Round 8
// 215.614 us; speedup vs baseline: 1.8012x; 1.1526x over previous
//
#include <hip/hip_runtime.h>

// ---------------------------------------------------------------------------
// CorefPairScorer: B=4, T=4096, D=768, N=256, HID=200 (padded to 224)
// h1(i,j) = relu(A[i] + Bv[j] + (emb_i*emb_j)@W1bot + b1)
// h2 = relu(h1@W2 + b2); s = h2@W3 + b3; masked softmax rows.
// R13 (2-wave blocks, acc[2][7], 5 w/SIMD): 148us, MfmaUtil 17% == model of
//   L2-latency-exposed K-loop (unroll-1 => next step's loads issue after
//   current MFMAs). R14: explicit 2-step register ping-pong: prefetch step
//   k+1's 7 weight + 3 emb loads BEFORE step k's MFMAs (T14 issue-early).
//   ~+80 VGPR -> __launch_bounds__(128,3). Same for phase-2 and node_mfma.
// ---------------------------------------------------------------------------

#define NB 4
#define NN 256
#define DD 768
#define TT 4096
#define HP 224
#define NTILES 14
#define KT1 24
#define KT2 7
#define TRI 136
#define ABS 448          // AB row stride (fp16): [A(224) | B(224)]
#define MTS 3584         // shorts per packed Mtile (16 rows x 224)

typedef _Float16 f16x8 __attribute__((ext_vector_type(8)));
typedef _Float16 f16x2 __attribute__((ext_vector_type(2)));
typedef __attribute__((ext_vector_type(4))) float f32x4;

union FragU { uint4 u; f16x8 h; };
union H2U { unsigned int u; f16x2 h; };

__device__ __forceinline__ unsigned int h2mul(unsigned int a, unsigned int b) {
    H2U x, y, r; x.u = a; y.u = b; r.h = x.h * y.h;   // v_pk_mul_f16
    return r.u;
}
__device__ __forceinline__ float hlo(unsigned int v) { H2U x; x.u = v; return (float)x.h[0]; }
__device__ __forceinline__ float hhi(unsigned int v) { H2U x; x.u = v; return (float)x.h[1]; }
__device__ __forceinline__ unsigned short f2h(float f) {
    _Float16 h = (_Float16)f;
    union { _Float16 h; unsigned short u; } r; r.h = h; return r.u;
}
__device__ __forceinline__ float h2f(unsigned short u) {
    union { unsigned short u; _Float16 h; } r; r.u = u; return (float)r.h;
}

// ---------------------------------------------------------------------------
// K0 (merged): weight swizzle (blocks 0..2211) + gather/cast (blocks 2212..3235)
//   frag layout: buf[((kt*NT+nt)*64+lane)*8+j] = W[kt*32+(lane>>4)*8+j][nt*16+(lane&15)]
// ---------------------------------------------------------------------------
__global__ void prep_all(const float* __restrict__ W1, const float* __restrict__ W2,
                         const float* __restrict__ ee, const int* __restrict__ eidx,
                         unsigned short* __restrict__ w1n,
                         unsigned short* __restrict__ w1s,
                         unsigned short* __restrict__ w2s,
                         unsigned short* __restrict__ emb) {
    const int N1n = 24 * 28 * 512;   // 344064
    const int N1s = 24 * 14 * 512;   // 172032
    const int N2  = 7 * 14 * 512;    // 50176
    int bx = blockIdx.x;
    if (bx >= 2212) {                 // gather + fp32->fp16
        int g = bx - 2212;
        int b = g >> 8, n = g & 255;
        int t = eidx[b * NN + n];
        const float* src = ee + ((size_t)b * TT + t) * DD;
        unsigned short* dst = emb + ((size_t)b * NN + n) * DD;
        for (int e = threadIdx.x; e < DD; e += 256) dst[e] = f2h(src[e]);
        return;
    }
    int idx = bx * 256 + threadIdx.x;
    if (idx < N1n) {
        int j = idx & 7, lane = (idx >> 3) & 63, f = idx >> 9;
        int nt = f % 28, kt = f / 28;
        int k = kt * 32 + (lane >> 4) * 8 + j;     // 0..767
        int n = nt * 16 + (lane & 15);             // 0..447
        float v;
        if (n < HP) v = (n < 200) ? W1[(size_t)k * 200 + n] : 0.f;
        else { int c2 = n - HP; v = (c2 < 200) ? W1[(size_t)(768 + k) * 200 + c2] : 0.f; }
        w1n[idx] = f2h(v);
    } else if (idx < N1n + N1s) {
        int i2 = idx - N1n;
        int j = i2 & 7, lane = (i2 >> 3) & 63, f = i2 >> 9;
        int nt = f % NTILES, kt = f / NTILES;
        int k = kt * 32 + (lane >> 4) * 8 + j;
        int n = nt * 16 + (lane & 15);
        float v = (n < 200) ? W1[(size_t)(1536 + k) * 200 + n] : 0.f;
        w1s[i2] = f2h(v);
    } else if (idx < N1n + N1s + N2) {
        int i2 = idx - N1n - N1s;
        int j = i2 & 7, lane = (i2 >> 3) & 63, f = i2 >> 9;
        int nt = f % NTILES, kt = f / NTILES;
        int k = kt * 32 + (lane >> 4) * 8 + j;
        int n = nt * 16 + (lane & 15);
        float v = (k < 200 && n < 200) ? W2[(size_t)k * 200 + n] : 0.f;
        w2s[i2] = f2h(v);
    }
}

// ---------------------------------------------------------------------------
// K2: AB = emb(1024x768) @ [W1top|W1mid](768x448), fp16 MFMA, fp16 out.
//   256 one-wave blocks; register ping-pong prefetch (1 wave/CU => pure ILP).
// ---------------------------------------------------------------------------
__global__ __launch_bounds__(64)
void node_mfma(const unsigned short* __restrict__ emb,
               const unsigned short* __restrict__ w1n,
               unsigned short* __restrict__ AB) {
    int lane = threadIdx.x & 63;
    int q = lane >> 4, c = lane & 15;
    int mt = blockIdx.x >> 2;         // 0..63
    int ng = blockIdx.x & 3;          // 0..3
    int m0 = mt * 16;
    const uint4* ga = (const uint4*)emb + (size_t)(m0 + c) * 96;
    const uint4* gb = (const uint4*)w1n;

    f32x4 acc[7];
#pragma unroll
    for (int n = 0; n < 7; ++n) acc[n] = (f32x4){0.f, 0.f, 0.f, 0.f};

    uint4 aA, aB, bA[7], bB[7];
    aA = ga[q];
#pragma unroll
    for (int n = 0; n < 7; ++n) bA[n] = gb[((0 * 28 + ng * 7 + n) << 6) + lane];

#pragma unroll 1
    for (int kt = 0; kt < KT1; kt += 2) {
        aB = ga[(kt + 1) * 4 + q];
#pragma unroll
        for (int n = 0; n < 7; ++n) bB[n] = gb[(((kt + 1) * 28 + ng * 7 + n) << 6) + lane];
        {
            FragU a; a.u = aA;
#pragma unroll
            for (int n = 0; n < 7; ++n) {
                FragU bb; bb.u = bA[n];
                acc[n] = __builtin_amdgcn_mfma_f32_16x16x32_f16(a.h, bb.h, acc[n], 0, 0, 0);
            }
        }
        if (kt + 2 < KT1) {
            aA = ga[(kt + 2) * 4 + q];
#pragma unroll
            for (int n = 0; n < 7; ++n) bA[n] = gb[(((kt + 2) * 28 + ng * 7 + n) << 6) + lane];
        }
        {
            FragU a; a.u = aB;
#pragma unroll
            for (int n = 0; n < 7; ++n) {
                FragU bb; bb.u = bB[n];
                acc[n] = __builtin_amdgcn_mfma_f32_16x16x32_f16(a.h, bb.h, acc[n], 0, 0, 0);
            }
        }
    }
#pragma unroll
    for (int n = 0; n < 7; ++n) {
        int col = (ng * 7 + n) * 16 + c;
#pragma unroll
        for (int rr = 0; rr < 4; ++rr)
            AB[(size_t)(m0 + q * 4 + rr) * ABS + col] = f2h(acc[n][rr]);
    }
}

// ---------------------------------------------------------------------------
// K3: pair MLP. Block = 128 threads = 2 waves (the nh pair) for one
//   (tile, i-row-pair). Wave nh: rows {iA,iB}, ntile-half nh, acc[2][7].
//   R14: 2-step register ping-pong in phase1/phase2 K-loops.
// ---------------------------------------------------------------------------
__global__ __launch_bounds__(128, 3)
void pair_wave(
    const unsigned short* __restrict__ emb,
    const unsigned short* __restrict__ w1s,
    const unsigned short* __restrict__ w2s,
    const unsigned short* __restrict__ AB,
    const float* __restrict__ b1, const float* __restrict__ b2,
    const float* __restrict__ W3, const float* __restrict__ b3,
    float* __restrict__ S) {
    int bid = blockIdx.x;
    int rp = bid / 544;               // 0..7 : i-row-pair within tile
    int g = bid % 544;                // tile id; mates 544 apart (544%8==0)
    int b = g / TRI;
    int r = g % TRI;
    int ti = (int)((sqrtf(8.f * (float)r + 1.f) - 1.f) * 0.5f);
    while ((ti + 1) * (ti + 2) / 2 <= r) ++ti;
    while (ti * (ti + 1) / 2 > r) --ti;
    int tj = r - ti * (ti + 1) / 2;
    int i0 = ti << 4, j0 = tj << 4;

    int tid = threadIdx.x;
    int lane = tid & 63;
    int nh = tid >> 6;                // 0..1 (ntile half)
    int q = lane >> 4, c = lane & 15;
    int iA = i0 + rp * 2, iB = iA + 1;

    __shared__ __align__(16) unsigned short smH[2 * MTS];   // 14336 B
    __shared__ float sred[2][32];                           //   256 B
    unsigned short* slot0 = smH;
    unsigned short* slot1 = smH + MTS;

    const uint4* w1f = (const uint4*)w1s;
    const uint4* w2f = (const uint4*)w2s;
    const uint4* gI0 = (const uint4*)(emb + ((size_t)b * NN + iA) * DD);
    const uint4* gI1 = (const uint4*)(emb + ((size_t)b * NN + iB) * DD);
    const uint4* gJc = (const uint4*)(emb + ((size_t)b * NN + j0 + c) * DD);

    // ---- phase 1: acc[2][7] over K=768, ping-pong prefetch ----
    f32x4 acc[2][7];
#pragma unroll
    for (int t = 0; t < 2; ++t)
#pragma unroll
        for (int n = 0; n < 7; ++n)
            acc[t][n] = (f32x4){0.f, 0.f, 0.f, 0.f};

    {
        uint4 bfrA[7], bfrB[7];
        uint4 ejA, e0A, e1A, ejB, e0B, e1B;
#pragma unroll
        for (int n = 0; n < 7; ++n) bfrA[n] = w1f[(nh * 7 + n) * 64 + lane];
        ejA = gJc[q]; e0A = gI0[q]; e1A = gI1[q];

#pragma unroll 1
        for (int kt = 0; kt < KT1; kt += 2) {
            // prefetch kt+1 -> B
#pragma unroll
            for (int n = 0; n < 7; ++n)
                bfrB[n] = w1f[((kt + 1) * NTILES + nh * 7 + n) * 64 + lane];
            ejB = gJc[(kt + 1) * 4 + q]; e0B = gI0[(kt + 1) * 4 + q]; e1B = gI1[(kt + 1) * 4 + q];
            // compute kt (A)
            {
                FragU a0, a1;
                a0.u.x = h2mul(e0A.x, ejA.x); a0.u.y = h2mul(e0A.y, ejA.y);
                a0.u.z = h2mul(e0A.z, ejA.z); a0.u.w = h2mul(e0A.w, ejA.w);
                a1.u.x = h2mul(e1A.x, ejA.x); a1.u.y = h2mul(e1A.y, ejA.y);
                a1.u.z = h2mul(e1A.z, ejA.z); a1.u.w = h2mul(e1A.w, ejA.w);
#pragma unroll
                for (int n = 0; n < 7; ++n) {
                    FragU bb; bb.u = bfrA[n];
                    acc[0][n] = __builtin_amdgcn_mfma_f32_16x16x32_f16(a0.h, bb.h, acc[0][n], 0, 0, 0);
                    acc[1][n] = __builtin_amdgcn_mfma_f32_16x16x32_f16(a1.h, bb.h, acc[1][n], 0, 0, 0);
                }
            }
            // prefetch kt+2 -> A
            if (kt + 2 < KT1) {
#pragma unroll
                for (int n = 0; n < 7; ++n)
                    bfrA[n] = w1f[((kt + 2) * NTILES + nh * 7 + n) * 64 + lane];
                ejA = gJc[(kt + 2) * 4 + q]; e0A = gI0[(kt + 2) * 4 + q]; e1A = gI1[(kt + 2) * 4 + q];
            }
            // compute kt+1 (B)
            {
                FragU a0, a1;
                a0.u.x = h2mul(e0B.x, ejB.x); a0.u.y = h2mul(e0B.y, ejB.y);
                a0.u.z = h2mul(e0B.z, ejB.z); a0.u.w = h2mul(e0B.w, ejB.w);
                a1.u.x = h2mul(e1B.x, ejB.x); a1.u.y = h2mul(e1B.y, ejB.y);
                a1.u.z = h2mul(e1B.z, ejB.z); a1.u.w = h2mul(e1B.w, ejB.w);
#pragma unroll
                for (int n = 0; n < 7; ++n) {
                    FragU bb; bb.u = bfrB[n];
                    acc[0][n] = __builtin_amdgcn_mfma_f32_16x16x32_f16(a0.h, bb.h, acc[0][n], 0, 0, 0);
                    acc[1][n] = __builtin_amdgcn_mfma_f32_16x16x32_f16(a1.h, bb.h, acc[1][n], 0, 0, 0);
                }
            }
        }
    }

    // ---- epilogue: h1 = relu(acc + A[i] + Bv[j] + b1) -> smH (nh half) ----
    {
        float af0[7], af1[7];
        unsigned int bvp[7][2];
#pragma unroll
        for (int n = 0; n < 7; ++n) {
            int h = ((nh * 7 + n) << 4) + c;
            float b1v = (h < 200) ? b1[h] : 0.f;
            af0[n] = h2f(AB[((size_t)b * NN + iA) * ABS + h]) + b1v;
            af1[n] = h2f(AB[((size_t)b * NN + iB) * ABS + h]) + b1v;
#pragma unroll
            for (int p = 0; p < 2; ++p) {
                unsigned int lo = AB[((size_t)b * NN + j0 + q * 4 + 2 * p) * ABS + HP + h];
                unsigned int hi = AB[((size_t)b * NN + j0 + q * 4 + 2 * p + 1) * ABS + HP + h];
                bvp[n][p] = (hi << 16) | lo;
            }
        }
#pragma unroll
        for (int n = 0; n < 7; ++n) {
            int h = ((nh * 7 + n) << 4) + c;
            int kk2 = h >> 5, q2 = (h >> 3) & 3, j2 = h & 7;
            int fa = ((kk2 * 4 + q2) << 7) + j2;        // + jj*8 below
#pragma unroll
            for (int rr = 0; rr < 4; ++rr) {
                float bvf = (rr & 1) ? hhi(bvp[n][rr >> 1]) : hlo(bvp[n][rr >> 1]);
                int ad = fa + ((q * 4 + rr) << 3);
                slot0[ad] = f2h(fmaxf(acc[0][n][rr] + af0[n] + bvf, 0.f));
                slot1[ad] = f2h(fmaxf(acc[1][n][rr] + af1[n] + bvf, 0.f));
            }
        }
    }
    __syncthreads();   // B1: both h-halves of h1 in smH

    // ---- phase 2: acc2[2][7] over K=224, ping-pong weight prefetch ----
    f32x4 acc2[2][7];
#pragma unroll
    for (int t = 0; t < 2; ++t)
#pragma unroll
        for (int n = 0; n < 7; ++n)
            acc2[t][n] = (f32x4){0.f, 0.f, 0.f, 0.f};

    {
        uint4 bfrA[7], bfrB[7];
#pragma unroll
        for (int n = 0; n < 7; ++n) bfrA[n] = w2f[(nh * 7 + n) * 64 + lane];

#pragma unroll 1
        for (int kk = 0; kk < 6; kk += 2) {
#pragma unroll
            for (int n = 0; n < 7; ++n)
                bfrB[n] = w2f[((kk + 1) * NTILES + nh * 7 + n) * 64 + lane];
            {
                FragU a20, a21;
                a20.u = *(const uint4*)(&slot0[(((kk * 4 + q) * 16 + c) << 3)]);
                a21.u = *(const uint4*)(&slot1[(((kk * 4 + q) * 16 + c) << 3)]);
#pragma unroll
                for (int n = 0; n < 7; ++n) {
                    FragU bb; bb.u = bfrA[n];
                    acc2[0][n] = __builtin_amdgcn_mfma_f32_16x16x32_f16(a20.h, bb.h, acc2[0][n], 0, 0, 0);
                    acc2[1][n] = __builtin_amdgcn_mfma_f32_16x16x32_f16(a21.h, bb.h, acc2[1][n], 0, 0, 0);
                }
            }
#pragma unroll
            for (int n = 0; n < 7; ++n)
                bfrA[n] = w2f[((kk + 2) * NTILES + nh * 7 + n) * 64 + lane];
            {
                FragU a20, a21;
                a20.u = *(const uint4*)(&slot0[((((kk + 1) * 4 + q) * 16 + c) << 3)]);
                a21.u = *(const uint4*)(&slot1[((((kk + 1) * 4 + q) * 16 + c) << 3)]);
#pragma unroll
                for (int n = 0; n < 7; ++n) {
                    FragU bb; bb.u = bfrB[n];
                    acc2[0][n] = __builtin_amdgcn_mfma_f32_16x16x32_f16(a20.h, bb.h, acc2[0][n], 0, 0, 0);
                    acc2[1][n] = __builtin_amdgcn_mfma_f32_16x16x32_f16(a21.h, bb.h, acc2[1][n], 0, 0, 0);
                }
            }
        }
        // tail kk=6 (already in bfrA)
        {
            FragU a20, a21;
            a20.u = *(const uint4*)(&slot0[(((6 * 4 + q) * 16 + c) << 3)]);
            a21.u = *(const uint4*)(&slot1[(((6 * 4 + q) * 16 + c) << 3)]);
#pragma unroll
            for (int n = 0; n < 7; ++n) {
                FragU bb; bb.u = bfrA[n];
                acc2[0][n] = __builtin_amdgcn_mfma_f32_16x16x32_f16(a20.h, bb.h, acc2[0][n], 0, 0, 0);
                acc2[1][n] = __builtin_amdgcn_mfma_f32_16x16x32_f16(a21.h, bb.h, acc2[1][n], 0, 0, 0);
            }
        }
    }

    // ---- phase 3: partial dot relu(h2+b2).W3 over nh half -> sred ----
    {
        float b2v[7], w3v[7];
#pragma unroll
        for (int n = 0; n < 7; ++n) {
            int h = ((nh * 7 + n) << 4) + c;
            b2v[n] = (h < 200) ? b2[h] : 0.f;
            w3v[n] = (h < 200) ? W3[h] : 0.f;
        }
#pragma unroll
        for (int t = 0; t < 2; ++t) {
#pragma unroll
            for (int rr = 0; rr < 4; ++rr) {
                float part = 0.f;
#pragma unroll
                for (int n = 0; n < 7; ++n) {
                    float hv = fmaxf(acc2[t][n][rr] + b2v[n], 0.f);
                    part += hv * w3v[n];
                }
                part += __shfl_xor(part, 1);
                part += __shfl_xor(part, 2);
                part += __shfl_xor(part, 4);
                part += __shfl_xor(part, 8);
                if (c == 0)
                    sred[nh][t * 16 + q * 4 + rr] = part;
            }
        }
    }
    __syncthreads();   // B2: both partials in sred

    if (tid < 32) {
        int t = tid >> 4, jj = tid & 15;
        float s = sred[0][tid] + sred[1][tid] + b3[0];
        S[((size_t)b * NN + iA + t) * NN + j0 + jj] = s;
    }
}

// ---------------------------------------------------------------------------
// K4: masked softmax per row; diag logit = 0; invalid -> -1000
// ---------------------------------------------------------------------------
__global__ __launch_bounds__(256) void softmax_rows(const float* __restrict__ S,
                                                    float* __restrict__ out) {
    int b = blockIdx.x >> 8, i = blockIdx.x & 255;
    int j = threadIdx.x;
    int lane = j & 63, w = j >> 6;
    __shared__ float red[16];
    float x = (j < i) ? S[((size_t)b * NN + i) * NN + j] : ((j == i) ? 0.f : -1e30f);
    float m = x;
#pragma unroll
    for (int off = 32; off; off >>= 1) m = fmaxf(m, __shfl_xor(m, off));
    if (lane == 0) red[w] = m;
    __syncthreads();
    float mx = fmaxf(fmaxf(red[0], red[1]), fmaxf(red[2], red[3]));
    float e = (j <= i) ? __expf(x - mx) : 0.f;
    float s = e;
#pragma unroll
    for (int off = 32; off; off >>= 1) s += __shfl_xor(s, off);
    if (lane == 0) red[8 + w] = s;
    __syncthreads();
    float sum = red[8] + red[9] + red[10] + red[11];
    out[((size_t)b * NN + i) * NN + j] = (j <= i) ? (e / sum) : -1000.0f;
}

// ---------------------------------------------------------------------------
extern "C" void kernel_launch(void* const* d_in, const int* in_sizes, int n_in,
                              void* d_out, int out_size, void* d_ws, size_t ws_size,
                              hipStream_t stream) {
    const float* ee  = (const float*)d_in[0];
    const int*   eidx = (const int*)d_in[1];
    const float* W1  = (const float*)d_in[2];
    const float* b1  = (const float*)d_in[3];
    const float* W2  = (const float*)d_in[4];
    const float* b2  = (const float*)d_in[5];
    const float* W3  = (const float*)d_in[6];
    const float* b3  = (const float*)d_in[7];
    float* out = (float*)d_out;

    char* p = (char*)d_ws;
    unsigned short* emb = (unsigned short*)p; p += (size_t)NB * NN * DD * 2;       // 1.5 MB
    unsigned short* w1n = (unsigned short*)p; p += (size_t)24 * 28 * 512 * 2;      // 672 KB
    unsigned short* w1s = (unsigned short*)p; p += (size_t)24 * 14 * 512 * 2;      // 336 KB
    unsigned short* w2s = (unsigned short*)p; p += (size_t)7 * 14 * 512 * 2;       // 98 KB
    unsigned short* AB  = (unsigned short*)p; p += (size_t)NB * NN * ABS * 2;      // 896 KB
    float* S  = (float*)p; p += (size_t)NB * NN * NN * 4;                           // 1 MB

    prep_all<<<3236, 256, 0, stream>>>(W1, W2, ee, eidx, w1n, w1s, w2s, emb);
    node_mfma<<<256, 64, 0, stream>>>(emb, w1n, AB);
    pair_wave<<<4352, 128, 0, stream>>>(emb, w1s, w2s, AB, b1, b2, W3, b3, S);
    softmax_rows<<<NB * NN, 256, 0, stream>>>(S, out);
}

// Round 9
// 209.305 us; speedup vs baseline: 1.8555x; 1.0301x over previous
//
#include <hip/hip_runtime.h>

// ---------------------------------------------------------------------------
// CorefPairScorer: B=4, T=4096, D=768, N=256, HID=200 (padded to 224)
// h1(i,j) = relu(A[i] + Bv[j] + (emb_i*emb_j)@W1bot + b1)
// h2 = relu(h1@W2 + b2); s = h2@W3 + b3; masked softmax rows.
// R14 (2-wave blocks, ping-pong): 119us, MfmaUtil 22%, no spill. L2 analysis:
//   weight stream ~18 TB/s = 52% of L2 peak -> BW-queueing, not pure latency.
// R15: 4 i-rows/wave (acc[4][7]): same 7 weight loads feed 28 MFMA (2x
//   density), L2 weight traffic halves (->26% of peak). 2176 blocks.
//   ~240 total regs -> 2 waves/SIMD, launch_bounds(128,2) (no cap-spill).
//   Named ping-pong buffer sets, unroll 1, static indices throughout.
// ---------------------------------------------------------------------------

#define NB 4
#define NN 256
#define DD 768
#define TT 4096
#define HP 224
#define NTILES 14
#define KT1 24
#define KT2 7
#define TRI 136
#define ABS 448          // AB row stride (fp16): [A(224) | B(224)]
#define MTS 3584         // shorts per packed Mtile (16 rows x 224)

typedef _Float16 f16x8 __attribute__((ext_vector_type(8)));
typedef _Float16 f16x2 __attribute__((ext_vector_type(2)));
typedef __attribute__((ext_vector_type(4))) float f32x4;

union FragU { uint4 u; f16x8 h; };
union H2U { unsigned int u; f16x2 h; };

__device__ __forceinline__ unsigned int h2mul(unsigned int a, unsigned int b) {
    H2U x, y, r; x.u = a; y.u = b; r.h = x.h * y.h;   // v_pk_mul_f16
    return r.u;
}
__device__ __forceinline__ float hlo(unsigned int v) { H2U x; x.u = v; return (float)x.h[0]; }
__device__ __forceinline__ float hhi(unsigned int v) { H2U x; x.u = v; return (float)x.h[1]; }
__device__ __forceinline__ unsigned short f2h(float f) {
    _Float16 h = (_Float16)f;
    union { _Float16 h; unsigned short u; } r; r.h = h; return r.u;
}
__device__ __forceinline__ float h2f(unsigned short u) {
    union { unsigned short u; _Float16 h; } r; r.u = u; return (float)r.h;
}

// ---------------------------------------------------------------------------
// K0 (merged): weight swizzle (blocks 0..2211) + gather/cast (blocks 2212..3235)
//   frag layout: buf[((kt*NT+nt)*64+lane)*8+j] = W[kt*32+(lane>>4)*8+j][nt*16+(lane&15)]
// ---------------------------------------------------------------------------
__global__ void prep_all(const float* __restrict__ W1, const float* __restrict__ W2,
                         const float* __restrict__ ee, const int* __restrict__ eidx,
                         unsigned short* __restrict__ w1n,
                         unsigned short* __restrict__ w1s,
                         unsigned short* __restrict__ w2s,
                         unsigned short* __restrict__ emb) {
    const int N1n = 24 * 28 * 512;   // 344064
    const int N1s = 24 * 14 * 512;   // 172032
    const int N2  = 7 * 14 * 512;    // 50176
    int bx = blockIdx.x;
    if (bx >= 2212) {                 // gather + fp32->fp16
        int g = bx - 2212;
        int b = g >> 8, n = g & 255;
        int t = eidx[b * NN + n];
        const float* src = ee + ((size_t)b * TT + t) * DD;
        unsigned short* dst = emb + ((size_t)b * NN + n) * DD;
        for (int e = threadIdx.x; e < DD; e += 256) dst[e] = f2h(src[e]);
        return;
    }
    int idx = bx * 256 + threadIdx.x;
    if (idx < N1n) {
        int j = idx & 7, lane = (idx >> 3) & 63, f = idx >> 9;
        int nt = f % 28, kt = f / 28;
        int k = kt * 32 + (lane >> 4) * 8 + j;     // 0..767
        int n = nt * 16 + (lane & 15);             // 0..447
        float v;
        if (n < HP) v = (n < 200) ? W1[(size_t)k * 200 + n] : 0.f;
        else { int c2 = n - HP; v = (c2 < 200) ? W1[(size_t)(768 + k) * 200 + c2] : 0.f; }
        w1n[idx] = f2h(v);
    } else if (idx < N1n + N1s) {
        int i2 = idx - N1n;
        int j = i2 & 7, lane = (i2 >> 3) & 63, f = i2 >> 9;
        int nt = f % NTILES, kt = f / NTILES;
        int k = kt * 32 + (lane >> 4) * 8 + j;
        int n = nt * 16 + (lane & 15);
        float v = (n < 200) ? W1[(size_t)(1536 + k) * 200 + n] : 0.f;
        w1s[i2] = f2h(v);
    } else if (idx < N1n + N1s + N2) {
        int i2 = idx - N1n - N1s;
        int j = i2 & 7, lane = (i2 >> 3) & 63, f = i2 >> 9;
        int nt = f % NTILES, kt = f / NTILES;
        int k = kt * 32 + (lane >> 4) * 8 + j;
        int n = nt * 16 + (lane & 15);
        float v = (k < 200 && n < 200) ? W2[(size_t)k * 200 + n] : 0.f;
        w2s[i2] = f2h(v);
    }
}

// ---------------------------------------------------------------------------
// K2: AB = emb(1024x768) @ [W1top|W1mid](768x448), fp16 MFMA, fp16 out.
//   256 one-wave blocks; register ping-pong prefetch.
// ---------------------------------------------------------------------------
__global__ __launch_bounds__(64)
void node_mfma(const unsigned short* __restrict__ emb,
               const unsigned short* __restrict__ w1n,
               unsigned short* __restrict__ AB) {
    int lane = threadIdx.x & 63;
    int q = lane >> 4, c = lane & 15;
    int mt = blockIdx.x >> 2;         // 0..63
    int ng = blockIdx.x & 3;          // 0..3
    int m0 = mt * 16;
    const uint4* ga = (const uint4*)emb + (size_t)(m0 + c) * 96;
    const uint4* gb = (const uint4*)w1n;

    f32x4 acc[7];
#pragma unroll
    for (int n = 0; n < 7; ++n) acc[n] = (f32x4){0.f, 0.f, 0.f, 0.f};

    uint4 aA, aB, bA[7], bB[7];
    aA = ga[q];
#pragma unroll
    for (int n = 0; n < 7; ++n) bA[n] = gb[((0 * 28 + ng * 7 + n) << 6) + lane];

#pragma unroll 1
    for (int kt = 0; kt < KT1; kt += 2) {
        aB = ga[(kt + 1) * 4 + q];
#pragma unroll
        for (int n = 0; n < 7; ++n) bB[n] = gb[(((kt + 1) * 28 + ng * 7 + n) << 6) + lane];
        {
            FragU a; a.u = aA;
#pragma unroll
            for (int n = 0; n < 7; ++n) {
                FragU bb; bb.u = bA[n];
                acc[n] = __builtin_amdgcn_mfma_f32_16x16x32_f16(a.h, bb.h, acc[n], 0, 0, 0);
            }
        }
        if (kt + 2 < KT1) {
            aA = ga[(kt + 2) * 4 + q];
#pragma unroll
            for (int n = 0; n < 7; ++n) bA[n] = gb[(((kt + 2) * 28 + ng * 7 + n) << 6) + lane];
        }
        {
            FragU a; a.u = aB;
#pragma unroll
            for (int n = 0; n < 7; ++n) {
                FragU bb; bb.u = bB[n];
                acc[n] = __builtin_amdgcn_mfma_f32_16x16x32_f16(a.h, bb.h, acc[n], 0, 0, 0);
            }
        }
    }
#pragma unroll
    for (int n = 0; n < 7; ++n) {
        int col = (ng * 7 + n) * 16 + c;
#pragma unroll
        for (int rr = 0; rr < 4; ++rr)
            AB[(size_t)(m0 + q * 4 + rr) * ABS + col] = f2h(acc[n][rr]);
    }
}

// ---------------------------------------------------------------------------
// K3: pair MLP. Block = 128 threads = 2 waves (the nh pair) for one
//   (tile, 4-i-row group rp). Wave nh: rows iA..iD = i0+rp*4+{0..3},
//   ntile-half nh, acc[4][7] (28 MFMA per 7 weight loads).
//   Phase1 ping-pong (weights+emb), epilogue -> smH (4 slots) -> B1 ->
//   phase2 acc2[4][7] ping-pong -> phase3 -> B2 -> store 64 pairs.
// ---------------------------------------------------------------------------
__global__ __launch_bounds__(128, 2)
void pair_wave(
    const unsigned short* __restrict__ emb,
    const unsigned short* __restrict__ w1s,
    const unsigned short* __restrict__ w2s,
    const unsigned short* __restrict__ AB,
    const float* __restrict__ b1, const float* __restrict__ b2,
    const float* __restrict__ W3, const float* __restrict__ b3,
    float* __restrict__ S) {
    int bid = blockIdx.x;
    int rp = bid / 544;               // 0..3 : 4-row group within tile
    int g = bid % 544;                // tile id; mates 544 apart (544%8==0)
    int b = g / TRI;
    int r = g % TRI;
    int ti = (int)((sqrtf(8.f * (float)r + 1.f) - 1.f) * 0.5f);
    while ((ti + 1) * (ti + 2) / 2 <= r) ++ti;
    while (ti * (ti + 1) / 2 > r) --ti;
    int tj = r - ti * (ti + 1) / 2;
    int i0 = ti << 4, j0 = tj << 4;

    int tid = threadIdx.x;
    int lane = tid & 63;
    int nh = tid >> 6;                // 0..1 (ntile half)
    int q = lane >> 4, c = lane & 15;
    int iA = i0 + rp * 4;             // rows iA..iA+3

    __shared__ __align__(16) unsigned short smH[4 * MTS];   // 28672 B (4 slots)
    __shared__ float sred[2][64];                           //   512 B

    const uint4* w1f = (const uint4*)w1s;
    const uint4* w2f = (const uint4*)w2s;
    const uint4* gI[4];
#pragma unroll
    for (int t = 0; t < 4; ++t)
        gI[t] = (const uint4*)(emb + ((size_t)b * NN + iA + t) * DD);
    const uint4* gJc = (const uint4*)(emb + ((size_t)b * NN + j0 + c) * DD);

    // ---- phase 1: acc[4][7] over K=768, ping-pong prefetch ----
    f32x4 acc[4][7];
#pragma unroll
    for (int t = 0; t < 4; ++t)
#pragma unroll
        for (int n = 0; n < 7; ++n)
            acc[t][n] = (f32x4){0.f, 0.f, 0.f, 0.f};

    {
        uint4 bfrA[7], bfrB[7];
        uint4 ejA, ejB, eA[4], eB[4];
#pragma unroll
        for (int n = 0; n < 7; ++n) bfrA[n] = w1f[(nh * 7 + n) * 64 + lane];
        ejA = gJc[q];
#pragma unroll
        for (int t = 0; t < 4; ++t) eA[t] = gI[t][q];

#pragma unroll 1
        for (int kt = 0; kt < KT1; kt += 2) {
            // prefetch kt+1 -> B
#pragma unroll
            for (int n = 0; n < 7; ++n)
                bfrB[n] = w1f[((kt + 1) * NTILES + nh * 7 + n) * 64 + lane];
            ejB = gJc[(kt + 1) * 4 + q];
#pragma unroll
            for (int t = 0; t < 4; ++t) eB[t] = gI[t][(kt + 1) * 4 + q];
            // compute kt (A)
#pragma unroll
            for (int t = 0; t < 4; ++t) {
                FragU a;
                a.u.x = h2mul(eA[t].x, ejA.x); a.u.y = h2mul(eA[t].y, ejA.y);
                a.u.z = h2mul(eA[t].z, ejA.z); a.u.w = h2mul(eA[t].w, ejA.w);
#pragma unroll
                for (int n = 0; n < 7; ++n) {
                    FragU bb; bb.u = bfrA[n];
                    acc[t][n] = __builtin_amdgcn_mfma_f32_16x16x32_f16(a.h, bb.h, acc[t][n], 0, 0, 0);
                }
            }
            // prefetch kt+2 -> A
            if (kt + 2 < KT1) {
#pragma unroll
                for (int n = 0; n < 7; ++n)
                    bfrA[n] = w1f[((kt + 2) * NTILES + nh * 7 + n) * 64 + lane];
                ejA = gJc[(kt + 2) * 4 + q];
#pragma unroll
                for (int t = 0; t < 4; ++t) eA[t] = gI[t][(kt + 2) * 4 + q];
            }
            // compute kt+1 (B)
#pragma unroll
            for (int t = 0; t < 4; ++t) {
                FragU a;
                a.u.x = h2mul(eB[t].x, ejB.x); a.u.y = h2mul(eB[t].y, ejB.y);
                a.u.z = h2mul(eB[t].z, ejB.z); a.u.w = h2mul(eB[t].w, ejB.w);
#pragma unroll
                for (int n = 0; n < 7; ++n) {
                    FragU bb; bb.u = bfrB[n];
                    acc[t][n] = __builtin_amdgcn_mfma_f32_16x16x32_f16(a.h, bb.h, acc[t][n], 0, 0, 0);
                }
            }
        }
    }

    // ---- epilogue: h1 = relu(acc + A[i] + Bv[j] + b1) -> smH (nh half) ----
    {
        unsigned int bvp[7][2];
#pragma unroll
        for (int n = 0; n < 7; ++n) {
            int h = ((nh * 7 + n) << 4) + c;
#pragma unroll
            for (int p = 0; p < 2; ++p) {
                unsigned int lo = AB[((size_t)b * NN + j0 + q * 4 + 2 * p) * ABS + HP + h];
                unsigned int hi = AB[((size_t)b * NN + j0 + q * 4 + 2 * p + 1) * ABS + HP + h];
                bvp[n][p] = (hi << 16) | lo;
            }
        }
#pragma unroll
        for (int t = 0; t < 4; ++t) {
            unsigned short* slot = &smH[t * MTS];
#pragma unroll
            for (int n = 0; n < 7; ++n) {
                int h = ((nh * 7 + n) << 4) + c;
                float b1v = (h < 200) ? b1[h] : 0.f;
                float af = h2f(AB[((size_t)b * NN + iA + t) * ABS + h]) + b1v;
                int kk2 = h >> 5, q2 = (h >> 3) & 3, j2 = h & 7;
                int fa = ((kk2 * 4 + q2) << 7) + j2;        // + jj*8 below
#pragma unroll
                for (int rr = 0; rr < 4; ++rr) {
                    float bvf = (rr & 1) ? hhi(bvp[n][rr >> 1]) : hlo(bvp[n][rr >> 1]);
                    slot[fa + ((q * 4 + rr) << 3)] =
                        f2h(fmaxf(acc[t][n][rr] + af + bvf, 0.f));
                }
            }
        }
    }
    __syncthreads();   // B1: both h-halves of all 4 slots in smH

    // ---- phase 2: acc2[4][7] over K=224, ping-pong weight prefetch ----
    f32x4 acc2[4][7];
#pragma unroll
    for (int t = 0; t < 4; ++t)
#pragma unroll
        for (int n = 0; n < 7; ++n)
            acc2[t][n] = (f32x4){0.f, 0.f, 0.f, 0.f};

    {
        uint4 bfrA[7], bfrB[7];
#pragma unroll
        for (int n = 0; n < 7; ++n) bfrA[n] = w2f[(nh * 7 + n) * 64 + lane];

#pragma unroll 1
        for (int kk = 0; kk < 6; kk += 2) {
#pragma unroll
            for (int n = 0; n < 7; ++n)
                bfrB[n] = w2f[((kk + 1) * NTILES + nh * 7 + n) * 64 + lane];
#pragma unroll
            for (int t = 0; t < 4; ++t) {
                FragU a2;
                a2.u = *(const uint4*)(&smH[t * MTS + (((kk * 4 + q) * 16 + c) << 3)]);
#pragma unroll
                for (int n = 0; n < 7; ++n) {
                    FragU bb; bb.u = bfrA[n];
                    acc2[t][n] = __builtin_amdgcn_mfma_f32_16x16x32_f16(a2.h, bb.h, acc2[t][n], 0, 0, 0);
                }
            }
#pragma unroll
            for (int n = 0; n < 7; ++n)
                bfrA[n] = w2f[((kk + 2) * NTILES + nh * 7 + n) * 64 + lane];
#pragma unroll
            for (int t = 0; t < 4; ++t) {
                FragU a2;
                a2.u = *(const uint4*)(&smH[t * MTS + ((((kk + 1) * 4 + q) * 16 + c) << 3)]);
#pragma unroll
                for (int n = 0; n < 7; ++n) {
                    FragU bb; bb.u = bfrB[n];
                    acc2[t][n] = __builtin_amdgcn_mfma_f32_16x16x32_f16(a2.h, bb.h, acc2[t][n], 0, 0, 0);
                }
            }
        }
        // tail kk=6 (already in bfrA)
#pragma unroll
        for (int t = 0; t < 4; ++t) {
            FragU a2;
            a2.u = *(const uint4*)(&smH[t * MTS + (((6 * 4 + q) * 16 + c) << 3)]);
#pragma unroll
            for (int n = 0; n < 7; ++n) {
                FragU bb; bb.u = bfrA[n];
                acc2[t][n] = __builtin_amdgcn_mfma_f32_16x16x32_f16(a2.h, bb.h, acc2[t][n], 0, 0, 0);
            }
        }
    }

    // ---- phase 3: partial dot relu(h2+b2).W3 over nh half -> sred ----
    {
        float b2v[7], w3v[7];
#pragma unroll
        for (int n = 0; n < 7; ++n) {
            int h = ((nh * 7 + n) << 4) + c;
            b2v[n] = (h < 200) ? b2[h] : 0.f;
            w3v[n] = (h < 200) ? W3[h] : 0.f;
        }
#pragma unroll
        for (int t = 0; t < 4; ++t) {
#pragma unroll
            for (int rr = 0; rr < 4; ++rr) {
                float part = 0.f;
#pragma unroll
                for (int n = 0; n < 7; ++n) {
                    float hv = fmaxf(acc2[t][n][rr] + b2v[n], 0.f);
                    part += hv * w3v[n];
                }
                part += __shfl_xor(part, 1);
                part += __shfl_xor(part, 2);
                part += __shfl_xor(part, 4);
                part += __shfl_xor(part, 8);
                if (c == 0)
                    sred[nh][t * 16 + q * 4 + rr] = part;
            }
        }
    }
    __syncthreads();   // B2: both partials in sred

    if (tid < 64) {
        int t = tid >> 4, jj = tid & 15;
        float s = sred[0][tid] + sred[1][tid] + b3[0];
        S[((size_t)b * NN + iA + t) * NN + j0 + jj] = s;
    }
}

// ---------------------------------------------------------------------------
// K4: masked softmax per row; diag logit = 0; invalid -> -1000
// ---------------------------------------------------------------------------
__global__ __launch_bounds__(256) void softmax_rows(const float* __restrict__ S,
                                                    float* __restrict__ out) {
    int b = blockIdx.x >> 8, i = blockIdx.x & 255;
    int j = threadIdx.x;
    int lane = j & 63, w = j >> 6;
    __shared__ float red[16];
    float x = (j < i) ? S[((size_t)b * NN + i) * NN + j] : ((j == i) ? 0.f : -1e30f);
    float m = x;
#pragma unroll
    for (int off = 32; off; off >>= 1) m = fmaxf(m, __shfl_xor(m, off));
    if (lane == 0) red[w] = m;
    __syncthreads();
    float mx = fmaxf(fmaxf(red[0], red[1]), fmaxf(red[2], red[3]));
    float e = (j <= i) ? __expf(x - mx) : 0.f;
    float s = e;
#pragma unroll
    for (int off = 32; off; off >>= 1) s += __shfl_xor(s, off);
    if (lane == 0) red[8 + w] = s;
    __syncthreads();
    float sum = red[8] + red[9] + red[10] + red[11];
    out[((size_t)b * NN + i) * NN + j] = (j <= i) ? (e / sum) : -1000.0f;
}

// ---------------------------------------------------------------------------
extern "C" void kernel_launch(void* const* d_in, const int* in_sizes, int n_in,
                              void* d_out, int out_size, void* d_ws, size_t ws_size,
                              hipStream_t stream) {
    const float* ee  = (const float*)d_in[0];
    const int*   eidx = (const int*)d_in[1];
    const float* W1  = (const float*)d_in[2];
    const float* b1  = (const float*)d_in[3];
    const float* W2  = (const float*)d_in[4];
    const float* b2  = (const float*)d_in[5];
    const float* W3  = (const float*)d_in[6];
    const float* b3  = (const float*)d_in[7];
    float* out = (float*)d_out;

    char* p = (char*)d_ws;
    unsigned short* emb = (unsigned short*)p; p += (size_t)NB * NN * DD * 2;       // 1.5 MB
    unsigned short* w1n = (unsigned short*)p; p += (size_t)24 * 28 * 512 * 2;      // 672 KB
    unsigned short* w1s = (unsigned short*)p; p += (size_t)24 * 14 * 512 * 2;      // 336 KB
    unsigned short* w2s = (unsigned short*)p; p += (size_t)7 * 14 * 512 * 2;       // 98 KB
    unsigned short* AB  = (unsigned short*)p; p += (size_t)NB * NN * ABS * 2;      // 896 KB
    float* S  = (float*)p; p += (size_t)NB * NN * NN * 4;                           // 1 MB

    prep_all<<<3236, 256, 0, stream>>>(W1, W2, ee, eidx, w1n, w1s, w2s, emb);
    node_mfma<<<256, 64, 0, stream>>>(emb, w1n, AB);
    pair_wave<<<2176, 128, 0, stream>>>(emb, w1s, w2s, AB, b1, b2, W3, b3, S);
    softmax_rows<<<NB * NN, 256, 0, stream>>>(S, out);
}